// Round 11
// baseline (262.250 us; speedup 1.0000x reference)
//
#include <hip/hip_runtime.h>
#include <math.h>

typedef unsigned short u16;
typedef __attribute__((ext_vector_type(4))) float f32x4;
typedef __attribute__((ext_vector_type(16))) float f32x16;
typedef __attribute__((ext_vector_type(4))) unsigned short u16x4;
typedef __attribute__((ext_vector_type(8))) __bf16 bf16x8;

static constexpr int SS   = 2048;   // seq len
static constexpr int DD   = 1024;   // model dim
static constexpr int HH   = 16;     // heads
static constexpr int DH   = 64;     // head dim
static constexpr int NTOK = 4096;   // B*S
static constexpr int NQKV = 3072;

#define DEV static __device__ __forceinline__
#define GLD_AS1(p) ((__attribute__((address_space(1))) void*)(void*)(p))
#define GLD_AS3(p) ((__attribute__((address_space(3))) void*)(p))

// fused counted-wait + barrier (T4)
#define WAIT_BAR(N) asm volatile("s_waitcnt vmcnt(" #N ")\n\ts_barrier" ::: "memory")
#define BAR()       asm volatile("s_barrier" ::: "memory")

DEV u16 f2bf(float f) {
    union { float f; unsigned int i; } v; v.f = f;
    unsigned int r = v.i + 0x7fffu + ((v.i >> 16) & 1u);
    return (u16)(r >> 16);
}
DEV float bdec(u16 u) {
    union { unsigned int i; float f; } v; v.i = ((unsigned int)u) << 16; return v.f;
}

DEV f32x4 MFMA(bf16x8 a, bf16x8 b, f32x4 c) {
    return __builtin_amdgcn_mfma_f32_16x16x32_bf16(a, b, c, 0, 0, 0);
}
DEV f32x16 MFMA32(bf16x8 a, bf16x8 b, f32x16 c) {
    return __builtin_amdgcn_mfma_f32_32x32x16_bf16(a, b, c, 0, 0, 0);
}
DEV f32x16 zero16() {
    f32x16 z;
    #pragma unroll
    for (int i = 0; i < 16; i++) z[i] = 0.f;
    return z;
}

// ---------------- transpose fp32 [R][C] -> bf16 [C][R] ----------------
__global__ __launch_bounds__(256)
void k_transpose(const float* __restrict__ in, u16* __restrict__ out, int R, int C) {
    __shared__ float tile[32][33];
    int c0 = blockIdx.x * 32, r0 = blockIdx.y * 32;
    int tx = threadIdx.x, ty = threadIdx.y; // 32 x 8
    #pragma unroll
    for (int i = 0; i < 32; i += 8)
        tile[ty + i][tx] = in[(size_t)(r0 + ty + i) * C + c0 + tx];
    __syncthreads();
    #pragma unroll
    for (int i = 0; i < 32; i += 8)
        out[(size_t)(c0 + ty + i) * R + r0 + tx] = f2bf(tile[tx][ty + i]);
}

// ------------- bf16 V transpose: qkv v-cols [s][d] -> vT[bh][d][s] -------------
__global__ __launch_bounds__(256)
void k_transpose_v(const u16* __restrict__ qkv, u16* __restrict__ vT) {
    __shared__ u16 tile[32][33];
    int bid = blockIdx.x;
    int st = bid & 63;           // s tile (2048/32)
    int dt = (bid >> 6) & 1;     // d tile (64/32)
    int bh = bid >> 7;           // 0..31
    int b = bh >> 4, h = bh & 15;
    int s0 = st * 32, d0 = dt * 32;
    int tx = threadIdx.x & 31, ty = threadIdx.x >> 5;   // 32 x 8
    const u16* src = qkv + ((size_t)(b * SS + s0)) * NQKV + 2048 + h * DH + d0;
    #pragma unroll
    for (int i = 0; i < 32; i += 8)
        tile[ty + i][tx] = src[(size_t)(ty + i) * NQKV + tx];
    __syncthreads();
    u16* dst = vT + ((size_t)bh * DH + d0) * SS + s0;
    #pragma unroll
    for (int i = 0; i < 32; i += 8)
        dst[(size_t)(ty + i) * SS + tx] = tile[tx][ty + i];
}

// ---------------- layernorm fp32 -> bf16, one block per row ----------------
__global__ __launch_bounds__(256)
void k_layernorm(const float* __restrict__ x, const float* __restrict__ g,
                 const float* __restrict__ b, u16* __restrict__ out) {
    int row = blockIdx.x, t = threadIdx.x;
    const float4* xp = reinterpret_cast<const float4*>(x + (size_t)row * DD);
    float4 v = xp[t];
    float s = v.x + v.y + v.z + v.w;
    float q = v.x * v.x + v.y * v.y + v.z * v.z + v.w * v.w;
    #pragma unroll
    for (int m = 1; m < 64; m <<= 1) { s += __shfl_xor(s, m); q += __shfl_xor(q, m); }
    __shared__ float ps[4], pq[4];
    int w = t >> 6, l = t & 63;
    if (l == 0) { ps[w] = s; pq[w] = q; }
    __syncthreads();
    s = ps[0] + ps[1] + ps[2] + ps[3];
    q = pq[0] + pq[1] + pq[2] + pq[3];
    float mu = s * (1.0f / DD);
    float var = q * (1.0f / DD) - mu * mu;
    float rstd = rsqrtf(var + 1e-5f);
    float4 gv = reinterpret_cast<const float4*>(g)[t];
    float4 bv = reinterpret_cast<const float4*>(b)[t];
    u16x4 o;
    o.x = f2bf((v.x - mu) * rstd * gv.x + bv.x);
    o.y = f2bf((v.y - mu) * rstd * gv.y + bv.y);
    o.z = f2bf((v.z - mu) * rstd * gv.z + bv.z);
    o.w = f2bf((v.w - mu) * rstd * gv.w + bv.w);
    reinterpret_cast<u16x4*>(out + (size_t)row * DD)[t] = o;
}

// -------- fused split-K reduce + LN: X1 = x+P0+P1+bias; LNout = LN(X1) --------
__global__ __launch_bounds__(256)
void k_redln(const float* __restrict__ x, const u16* __restrict__ P0,
             const u16* __restrict__ P1, const float* __restrict__ bias,
             const float* __restrict__ g, const float* __restrict__ be,
             float* __restrict__ X1, u16* __restrict__ LNout) {
    int row = blockIdx.x, t = threadIdx.x;
    size_t i = (size_t)row * 256 + t;
    float4 xv = reinterpret_cast<const float4*>(x)[i];
    u16x4 a = reinterpret_cast<const u16x4*>(P0)[i];
    u16x4 bb = reinterpret_cast<const u16x4*>(P1)[i];
    float4 bv = reinterpret_cast<const float4*>(bias)[t];
    float4 v;
    v.x = xv.x + bdec(a.x) + bdec(bb.x) + bv.x;
    v.y = xv.y + bdec(a.y) + bdec(bb.y) + bv.y;
    v.z = xv.z + bdec(a.z) + bdec(bb.z) + bv.z;
    v.w = xv.w + bdec(a.w) + bdec(bb.w) + bv.w;
    reinterpret_cast<float4*>(X1)[i] = v;
    float s = v.x + v.y + v.z + v.w;
    float q = v.x * v.x + v.y * v.y + v.z * v.z + v.w * v.w;
    #pragma unroll
    for (int m = 1; m < 64; m <<= 1) { s += __shfl_xor(s, m); q += __shfl_xor(q, m); }
    __shared__ float ps[4], pq[4];
    int w = t >> 6, l = t & 63;
    if (l == 0) { ps[w] = s; pq[w] = q; }
    __syncthreads();
    s = ps[0] + ps[1] + ps[2] + ps[3];
    q = pq[0] + pq[1] + pq[2] + pq[3];
    float mu = s * (1.0f / DD);
    float var = q * (1.0f / DD) - mu * mu;
    float rstd = rsqrtf(var + 1e-5f);
    float4 gv = reinterpret_cast<const float4*>(g)[t];
    float4 ev = reinterpret_cast<const float4*>(be)[t];
    u16x4 o;
    o.x = f2bf((v.x - mu) * rstd * gv.x + ev.x);
    o.y = f2bf((v.y - mu) * rstd * gv.y + ev.y);
    o.z = f2bf((v.z - mu) * rstd * gv.z + ev.z);
    o.w = f2bf((v.w - mu) * rstd * gv.w + ev.w);
    reinterpret_cast<u16x4*>(LNout + (size_t)row * DD)[t] = o;
}

// ---------- 256x256 8-phase GEMM (8 waves, BK=64, counted vmcnt, T5) ----------
// C[M,N] = A[M,K] @ BT[N,K]^T. Wave (wr,wc) in 2x4 grid owns 128x64 output.
// Per K-tile: stage 8 loads -> vmcnt(8)+barrier -> 4 phases of
// {ds_read subtile; barrier; setprio1; 16 MFMA; setprio0; barrier}.
// MODE 0: qkv epilogue (scale q cols). MODE 2: tanh-GELU + bias.
template<int MODE>
__global__ __launch_bounds__(512, 2)
void k_gemm256(const u16* __restrict__ A, const u16* __restrict__ BT,
               u16* __restrict__ Cb, const float* __restrict__ bias,
               int M, int N, int K) {
    __shared__ __align__(128) char lds[2][65536];   // per buf: A 32KB | B 32KB
    const int t = threadIdx.x;
    const int w = t >> 6, l = t & 63;
    const int lg = l >> 4, lr = l & 15;
    const int m0 = blockIdx.y * 256, n0 = blockIdx.x * 256;
    const int wr = w >> 2, wc = w & 3;

    const int csw = ((l & 7) ^ (l >> 3)) << 3;   // pre-swizzled source col (elems)
    const int srow = l >> 3;
    const int swzc = (lr & 7) << 4;              // read-side byte xor

    f32x4 acc[8][4];
    #pragma unroll
    for (int i = 0; i < 8; i++)
        #pragma unroll
        for (int j = 0; j < 4; j++)
            acc[i][j] = (f32x4){0.f, 0.f, 0.f, 0.f};

    auto STAGE = [&](int buf, int kt) {
        char* base = lds[buf];
        #pragma unroll
        for (int i = 0; i < 4; i++) {
            const int chunk = w * 4 + i;          // 0..31 (8 rows each)
            const int r = chunk * 8 + srow;       // 0..255
            __builtin_amdgcn_global_load_lds(GLD_AS1(A  + (size_t)(m0 + r) * K + kt + csw),
                                             GLD_AS3(base + chunk * 1024), 16, 0, 0);
            __builtin_amdgcn_global_load_lds(GLD_AS1(BT + (size_t)(n0 + r) * K + kt + csw),
                                             GLD_AS3(base + 32768 + chunk * 1024), 16, 0, 0);
        }
    };

    STAGE(0, 0);
    int buf = 0;
    for (int kt = 0; kt < K; kt += 64) {
        if (kt + 64 < K) { STAGE(buf ^ 1, kt + 64); WAIT_BAR(8); }
        else            { WAIT_BAR(0); }
        const char* Abase = lds[buf];
        const char* Bbase = Abase + 32768;

        // B fragments: all 4 n-frags x 2 k-steps, reused across all 4 phases
        bf16x8 Bf[4][2];
        #pragma unroll
        for (int ni = 0; ni < 4; ni++)
            #pragma unroll
            for (int ks = 0; ks < 2; ks++)
                Bf[ni][ks] = *reinterpret_cast<const bf16x8*>(
                    Bbase + (wc * 64 + ni * 16 + lr) * 128 + ((ks * 64 + lg * 16) ^ swzc));

        #pragma unroll
        for (int mh = 0; mh < 4; mh++) {          // 4 phases, 2 m-frags each
            bf16x8 Af[2][2];
            #pragma unroll
            for (int mi2 = 0; mi2 < 2; mi2++)
                #pragma unroll
                for (int ks = 0; ks < 2; ks++)
                    Af[mi2][ks] = *reinterpret_cast<const bf16x8*>(
                        Abase + (wr * 128 + (mh * 2 + mi2) * 16 + lr) * 128 + ((ks * 64 + lg * 16) ^ swzc));
            BAR();
            __builtin_amdgcn_s_setprio(1);
            #pragma unroll
            for (int mi2 = 0; mi2 < 2; mi2++)
                #pragma unroll
                for (int ni = 0; ni < 4; ni++)
                    #pragma unroll
                    for (int ks = 0; ks < 2; ks++)
                        acc[mh * 2 + mi2][ni] = MFMA(Af[mi2][ks], Bf[ni][ks], acc[mh * 2 + mi2][ni]);
            __builtin_amdgcn_s_setprio(0);
            BAR();
        }
        buf ^= 1;
    }

    // epilogue
    #pragma unroll
    for (int mi = 0; mi < 8; mi++) {
        #pragma unroll
        for (int ni = 0; ni < 4; ni++) {
            int nn = n0 + wc * 64 + ni * 16 + lr;
            #pragma unroll
            for (int r = 0; r < 4; r++) {
                int mm = m0 + wr * 128 + mi * 16 + lg * 4 + r;
                float v = acc[mi][ni][r];
                if (MODE == 0) {
                    float sv = (nn < 1024) ? v * 0.18033688011112042f : v;
                    Cb[(size_t)mm * NQKV + nn] = f2bf(sv);
                } else {
                    float u = v + bias[nn];
                    float u3 = u * u * u;
                    float gl = u / (1.0f + exp2f(-2.3022077f * u - 0.10294276f * u3));
                    Cb[(size_t)mm * N + nn] = f2bf(gl);
                }
            }
        }
    }
}

// ---------------- 128x128 GEMM (split-K partials), 2-phase pipeline ----------
// MODE 3: split-K partials (grid.z=2): bf16 raw acc -> (z ? P1 : P0)
__global__ __launch_bounds__(256)
void k_gemm_sk(const u16* __restrict__ A, const u16* __restrict__ BT,
               u16* __restrict__ P0, u16* __restrict__ P1, int M, int N, int K) {
    __shared__ __align__(128) char lds[2][32768];
    const int t = threadIdx.x;
    const int w = t >> 6, l = t & 63;
    const int lg = l >> 4, lr = l & 15;
    const int m0 = blockIdx.y * 128, n0 = blockIdx.x * 128;
    const int wr = w >> 1, wc = w & 1;

    const int kh = K >> 1;
    const int kbeg = blockIdx.z * kh;
    const int kend = kbeg + kh;

    const int csw = ((l & 7) ^ (l >> 3)) << 3;
    const int chunk0 = w * 4;
    const int srow = (l >> 3);

    f32x4 acc[4][4];
    #pragma unroll
    for (int i = 0; i < 4; i++)
        #pragma unroll
        for (int j = 0; j < 4; j++)
            acc[i][j] = (f32x4){0.f, 0.f, 0.f, 0.f};

    #pragma unroll
    for (int i = 0; i < 4; i++) {
        const int chunk = chunk0 + i;
        const int r = chunk * 8 + srow;
        __builtin_amdgcn_global_load_lds(GLD_AS1(A  + (size_t)(m0 + r) * K + kbeg + csw),
                                         GLD_AS3(lds[0] + chunk * 1024), 16, 0, 0);
        __builtin_amdgcn_global_load_lds(GLD_AS1(BT + (size_t)(n0 + r) * K + kbeg + csw),
                                         GLD_AS3(lds[0] + 16384 + chunk * 1024), 16, 0, 0);
    }

    int buf = 0;
    for (int kt = kbeg; kt < kend; kt += 64) {
        if (kt + 64 < kend) {
            #pragma unroll
            for (int i = 0; i < 4; i++) {
                const int chunk = chunk0 + i;
                const int r = chunk * 8 + srow;
                __builtin_amdgcn_global_load_lds(GLD_AS1(A  + (size_t)(m0 + r) * K + kt + 64 + csw),
                                                 GLD_AS3(lds[buf ^ 1] + chunk * 1024), 16, 0, 0);
                __builtin_amdgcn_global_load_lds(GLD_AS1(BT + (size_t)(n0 + r) * K + kt + 64 + csw),
                                                 GLD_AS3(lds[buf ^ 1] + 16384 + chunk * 1024), 16, 0, 0);
            }
            WAIT_BAR(8);
        } else {
            WAIT_BAR(0);
        }
        const char* Al = lds[buf];
        const char* Bl = lds[buf] + 16384;
        #pragma unroll
        for (int s = 0; s < 2; s++) {
            const int swz = (s * 64 + lg * 16) ^ ((lr & 7) << 4);
            bf16x8 af[4], bfr[4];
            #pragma unroll
            for (int mi = 0; mi < 4; mi++)
                af[mi] = *reinterpret_cast<const bf16x8*>(Al + (wr * 64 + mi * 16 + lr) * 128 + swz);
            #pragma unroll
            for (int ni = 0; ni < 4; ni++)
                bfr[ni] = *reinterpret_cast<const bf16x8*>(Bl + (wc * 64 + ni * 16 + lr) * 128 + swz);
            #pragma unroll
            for (int mi = 0; mi < 4; mi++)
                #pragma unroll
                for (int ni = 0; ni < 4; ni++)
                    acc[mi][ni] = MFMA(af[mi], bfr[ni], acc[mi][ni]);
        }
        BAR();
        buf ^= 1;
    }

    u16* dst = blockIdx.z ? P1 : P0;
    #pragma unroll
    for (int mi = 0; mi < 4; mi++) {
        #pragma unroll
        for (int ni = 0; ni < 4; ni++) {
            int nn = n0 + wc * 64 + ni * 16 + lr;
            #pragma unroll
            for (int r = 0; r < 4; r++) {
                int mm = m0 + wr * 64 + mi * 16 + lg * 4 + r;
                dst[(size_t)mm * N + nn] = f2bf(acc[mi][ni][r]);
            }
        }
    }
}

// ------------- final split-K reduce: OUT = RES + P0 + P1 + bias ---------------
__global__ __launch_bounds__(256)
void k_ffreduce(const float* __restrict__ RES, const u16* __restrict__ P0,
                const u16* __restrict__ P1, const float* __restrict__ bias,
                float* __restrict__ OUT) {
    int i = blockIdx.x * 256 + threadIdx.x;      // float4 index
    float4 xv = reinterpret_cast<const float4*>(RES)[i];
    u16x4 a = reinterpret_cast<const u16x4*>(P0)[i];
    u16x4 b = reinterpret_cast<const u16x4*>(P1)[i];
    float4 bv = reinterpret_cast<const float4*>(bias)[i & (DD / 4 - 1)];
    float4 o;
    o.x = xv.x + bdec(a.x) + bdec(b.x) + bv.x;
    o.y = xv.y + bdec(a.y) + bdec(b.y) + bv.y;
    o.z = xv.z + bdec(a.z) + bdec(b.z) + bv.z;
    o.w = xv.w + bdec(a.w) + bdec(b.w) + bv.w;
    reinterpret_cast<float4*>(OUT)[i] = o;
}

// ------- flash attention, swapped-QK 32x32, KVBLK=64, cross-iter pipeline ------
__global__ __launch_bounds__(256)
void k_attn(const u16* __restrict__ qkv, const u16* __restrict__ vT,
            u16* __restrict__ out) {
    const int w = threadIdx.x >> 6, l = threadIdx.x & 63;
    const int q = l & 31, hi = l >> 5;
    const int task = (blockIdx.x & 7) * 64 + (blockIdx.x >> 3);  // 512-block bijection
    const int bh = task >> 4;                // 0..31 (4 heads per XCD)
    const int qg = task & 15;
    const int b = bh >> 4, h = bh & 15;
    const size_t rowbase = (size_t)b * SS;
    const int q0 = (qg * 4 + w) * 32;

    __shared__ __align__(128) u16 Kl[3][64 * 64];   // triple buffer (stage depth 2)
    __shared__ __align__(128) u16 Vl[2][64 * 64];   // double buffer

    const u16* kbase = qkv + rowbase * NQKV + 1024 + h * DH;
    const u16* vbase = vT + (size_t)bh * DH * SS;

    const int srow8 = l >> 3;
    const int sslot = (l & 7) ^ srow8;
    const int kr0 = w * 8 + srow8;
    const u16* kg0 = kbase + (size_t)kr0 * NQKV + sslot * 8;
    const u16* kg1 = kbase + (size_t)(kr0 + 32) * NQKV + sslot * 8;
    const u16* vg0 = vbase + (size_t)kr0 * SS + sslot * 8;
    const u16* vg1 = vbase + (size_t)(kr0 + 32) * SS + sslot * 8;
    const int chA = (w * 8) * 64, chB = (w * 8 + 32) * 64;

    const u16* qrow = qkv + (rowbase + q0 + q) * NQKV + h * DH + hi * 8;
    bf16x8 qf[4];
    #pragma unroll
    for (int ks = 0; ks < 4; ks++)
        qf[ks] = *reinterpret_cast<const bf16x8*>(qrow + ks * 16);
    asm volatile("s_waitcnt vmcnt(0)" ::: "memory");

    bf16x8 onesf;
    #pragma unroll
    for (int i = 0; i < 8; i++) onesf[i] = (__bf16)1.0f;

    f32x16 o0 = zero16(), o1 = zero16();
    f32x16 lacc = zero16();
    const int qsw = (q & 7) << 3;

    __builtin_amdgcn_global_load_lds(GLD_AS1(kg0), GLD_AS3((u16*)Kl[0] + chA), 16, 0, 0);
    __builtin_amdgcn_global_load_lds(GLD_AS1(kg1), GLD_AS3((u16*)Kl[0] + chB), 16, 0, 0);
    __builtin_amdgcn_global_load_lds(GLD_AS1(kg0 + (size_t)64 * NQKV), GLD_AS3((u16*)Kl[1] + chA), 16, 0, 0);
    __builtin_amdgcn_global_load_lds(GLD_AS1(kg1 + (size_t)64 * NQKV), GLD_AS3((u16*)Kl[1] + chB), 16, 0, 0);
    __builtin_amdgcn_global_load_lds(GLD_AS1(vg0), GLD_AS3((u16*)Vl[0] + chA), 16, 0, 0);
    __builtin_amdgcn_global_load_lds(GLD_AS1(vg1), GLD_AS3((u16*)Vl[0] + chB), 16, 0, 0);
    WAIT_BAR(4);

    f32x16 scA0 = zero16(), scA1 = zero16();
    {
        const u16* Kb = Kl[0];
        #pragma unroll
        for (int ks = 0; ks < 4; ks++) {
            const int off = (ks * 16 + hi * 8) ^ qsw;
            bf16x8 kf0 = *reinterpret_cast<const bf16x8*>(Kb + q * 64 + off);
            bf16x8 kf1 = *reinterpret_cast<const bf16x8*>(Kb + (q + 32) * 64 + off);
            scA0 = MFMA32(kf0, qf[ks], scA0);
            scA1 = MFMA32(kf1, qf[ks], scA1);
        }
    }

    int kRead = 1, vRead = 0;
    for (int i = 0; i < 32; ++i) {
        const int kStage = (kRead == 2) ? 0 : kRead + 1;
        if (i + 2 < 32) {
            const size_t koff = (size_t)(i + 2) * 64 * NQKV;
            __builtin_amdgcn_global_load_lds(GLD_AS1(kg0 + koff), GLD_AS3((u16*)Kl[kStage] + chA), 16, 0, 0);
            __builtin_amdgcn_global_load_lds(GLD_AS1(kg1 + koff), GLD_AS3((u16*)Kl[kStage] + chB), 16, 0, 0);
            WAIT_BAR(2);
        } else {
            WAIT_BAR(0);
        }
        if (i + 1 < 32) {
            const int voff = (i + 1) * 64;
            __builtin_amdgcn_global_load_lds(GLD_AS1(vg0 + voff), GLD_AS3((u16*)Vl[vRead ^ 1] + chA), 16, 0, 0);
            __builtin_amdgcn_global_load_lds(GLD_AS1(vg1 + voff), GLD_AS3((u16*)Vl[vRead ^ 1] + chB), 16, 0, 0);
        }

        f32x16 p0, p1;
        #pragma unroll
        for (int j = 0; j < 16; j++) p0[j] = exp2f(scA0[j]);
        #pragma unroll
        for (int j = 0; j < 16; j++) p1[j] = exp2f(scA1[j]);

        f32x16 stB0 = zero16(), stB1 = zero16();
        if (i + 1 < 32) {
            const u16* Kb = Kl[kRead];
            #pragma unroll
            for (int ks = 0; ks < 4; ks++) {
                const int off = (ks * 16 + hi * 8) ^ qsw;
                bf16x8 kf0 = *reinterpret_cast<const bf16x8*>(Kb + q * 64 + off);
                bf16x8 kf1 = *reinterpret_cast<const bf16x8*>(Kb + (q + 32) * 64 + off);
                stB0 = MFMA32(kf0, qf[ks], stB0);
                stB1 = MFMA32(kf1, qf[ks], stB1);
            }
        }

        union W { unsigned int u; __bf16 h[2]; };
        W pw[16];
        #pragma unroll
        for (int m = 0; m < 8; m++) {
            pw[m].h[0] = (__bf16)p0[2 * m];
            pw[m].h[1] = (__bf16)p0[2 * m + 1];
            pw[8 + m].h[0] = (__bf16)p1[2 * m];
            pw[8 + m].h[1] = (__bf16)p1[2 * m + 1];
        }
        bf16x8 pf[4];
        #pragma unroll
        for (int kk = 0; kk < 4; kk++) {
            const int base = (kk >> 1) * 8 + (kk & 1) * 4;
            unsigned int a0 = pw[base + 0].u, a1 = pw[base + 1].u;
            unsigned int b0 = pw[base + 2].u, b1 = pw[base + 3].u;
            unsigned int own0 = hi ? b0 : a0, own1 = hi ? b1 : a1;
            unsigned int snd0 = hi ? a0 : b0, snd1 = hi ? a1 : b1;
            unsigned int r0 = __shfl_xor(snd0, 32), r1 = __shfl_xor(snd1, 32);
            union F { unsigned int u[4]; bf16x8 v; } f;
            f.u[0] = hi ? r0 : own0;
            f.u[1] = hi ? r1 : own1;
            f.u[2] = hi ? own0 : r0;
            f.u[3] = hi ? own1 : r1;
            pf[kk] = f.v;
        }

        const u16* Vb = Vl[vRead];
        #pragma unroll
        for (int kk = 0; kk < 4; kk++) {
            const int off = (kk * 16 + hi * 8) ^ qsw;
            bf16x8 v0 = *reinterpret_cast<const bf16x8*>(Vb + q * 64 + off);
            bf16x8 v1 = *reinterpret_cast<const bf16x8*>(Vb + (q + 32) * 64 + off);
            lacc = MFMA32(onesf, pf[kk], lacc);
            o0 = MFMA32(v0, pf[kk], o0);
            o1 = MFMA32(v1, pf[kk], o1);
        }

        scA0 = stB0;
        scA1 = stB1;
        kRead = kStage;
        vRead ^= 1;
    }

    float invl = 1.0f / lacc[0];
    u16* orow = out + (rowbase + q0 + q) * DD + h * DH + hi * 4;
    #pragma unroll
    for (int a = 0; a < 4; a++) {
        u16x4 s0v, s1v;
        #pragma unroll
        for (int i = 0; i < 4; i++) {
            s0v[i] = f2bf(o0[4 * a + i] * invl);
            s1v[i] = f2bf(o1[4 * a + i] * invl);
        }
        *reinterpret_cast<u16x4*>(orow + 8 * a)      = s0v;
        *reinterpret_cast<u16x4*>(orow + 32 + 8 * a) = s1v;
    }
}

extern "C" void kernel_launch(void* const* d_in, const int* in_sizes, int n_in,
                              void* d_out, int out_size, void* d_ws, size_t ws_size,
                              hipStream_t stream) {
    (void)in_sizes; (void)n_in; (void)out_size; (void)ws_size;
    const float* x     = (const float*)d_in[0];
    const float* w_qkv = (const float*)d_in[1];
    const float* w_out = (const float*)d_in[2];
    const float* b_out = (const float*)d_in[3];
    const float* g1    = (const float*)d_in[4];
    const float* be1   = (const float*)d_in[5];
    const float* g2    = (const float*)d_in[6];
    const float* be2   = (const float*)d_in[7];
    const float* w_ff1 = (const float*)d_in[8];
    const float* b_ff1 = (const float*)d_in[9];
    const float* w_ff2 = (const float*)d_in[10];
    const float* b_ff2 = (const float*)d_in[11];

    char* ws = (char*)d_ws;
    u16*   W  = (u16*)(ws);                  //  8.39 MB  (weight^T scratch, reused)
    u16*   Hb = (u16*)(ws + 8388608);        //  8.39 MB  (LN1 out; later partials)
    u16*   QF = (u16*)(ws + 16777216);       // 33.55 MB  (qkv, later ffn act)
    u16*   VT = (u16*)(ws + 50331648);       //  8.39 MB  (v^T; later partials)
    u16*   AO = (u16*)(ws + 58720256);       //  8.39 MB  (attn out; later LN2 out)
    float* X1 = (float*)(ws + 67108864);     // 16.78 MB  (post-attn residual fp32)
    float* OUT = (float*)d_out;

    // LN1: x -> Hb
    k_layernorm<<<NTOK, 256, 0, stream>>>(x, g1, be1, Hb);
    // w_qkv^T
    k_transpose<<<dim3(3072 / 32, 1024 / 32), dim3(32, 8), 0, stream>>>(w_qkv, W, 1024, 3072);
    // qkv = Hb @ w_qkv  (256^2 8-phase; q cols pre-scaled; linear store)
    k_gemm256<0><<<dim3(3072 / 256, 4096 / 256), 512, 0, stream>>>(
        Hb, W, QF, nullptr, NTOK, NQKV, 1024);
    // V transpose (coalesced both sides)
    k_transpose_v<<<4096, 256, 0, stream>>>(QF, VT);
    // attention (512 blocks, XCD-swizzled, KVBLK=64, cross-iter pipelined)
    k_attn<<<512, 256, 0, stream>>>(QF, VT, AO);
    // w_out^T
    k_transpose<<<dim3(1024 / 32, 1024 / 32), dim3(32, 8), 0, stream>>>(w_out, W, 1024, 1024);
    // attn-out split-K x2: partials P0 -> Hb, P1 -> VT
    k_gemm_sk<<<dim3(1024 / 128, 4096 / 128, 2), 256, 0, stream>>>(
        AO, W, Hb, VT, NTOK, 1024, 1024);
    // fused: X1 = x + P0 + P1 + b_out ; AO = LN2(X1)
    k_redln<<<NTOK, 256, 0, stream>>>(x, Hb, VT, b_out, g2, be2, X1, AO);
    // w_ff1^T
    k_transpose<<<dim3(4096 / 32, 1024 / 32), dim3(32, 8), 0, stream>>>(w_ff1, W, 1024, 4096);
    // FFA = gelu(AO @ w_ff1 + b_ff1) -> QF   (256^2 8-phase)
    k_gemm256<2><<<dim3(4096 / 256, 4096 / 256), 512, 0, stream>>>(
        AO, W, QF, b_ff1, NTOK, 4096, 1024);
    // w_ff2^T
    k_transpose<<<dim3(1024 / 32, 4096 / 32), dim3(32, 8), 0, stream>>>(w_ff2, W, 4096, 1024);
    // ff2 split-K x2: partials P0 -> VT, P1 -> Hb
    k_gemm_sk<<<dim3(1024 / 128, 4096 / 128, 2), 256, 0, stream>>>(
        QF, W, VT, Hb, NTOK, 1024, 4096);
    // OUT = X1 + P0 + P1 + b_ff2
    k_ffreduce<<<NTOK * DD / 4 / 256, 256, 0, stream>>>(X1, VT, Hb, b_ff2, OUT);
}

// Round 12
// 253.444 us; speedup vs baseline: 1.0347x; 1.0347x over previous
//
#include <hip/hip_runtime.h>
#include <math.h>

typedef unsigned short u16;
typedef __attribute__((ext_vector_type(4))) float f32x4;
typedef __attribute__((ext_vector_type(16))) float f32x16;
typedef __attribute__((ext_vector_type(4))) unsigned short u16x4;
typedef __attribute__((ext_vector_type(8))) __bf16 bf16x8;

static constexpr int SS   = 2048;   // seq len
static constexpr int DD   = 1024;   // model dim
static constexpr int HH   = 16;     // heads
static constexpr int DH   = 64;     // head dim
static constexpr int NTOK = 4096;   // B*S
static constexpr int NQKV = 3072;

#define DEV static __device__ __forceinline__
#define GLD_AS1(p) ((__attribute__((address_space(1))) void*)(void*)(p))
#define GLD_AS3(p) ((__attribute__((address_space(3))) void*)(p))

// fused counted-wait + barrier (T4)
#define WAIT_BAR(N) asm volatile("s_waitcnt vmcnt(" #N ")\n\ts_barrier" ::: "memory")
#define BAR()       asm volatile("s_barrier" ::: "memory")

DEV u16 f2bf(float f) {
    union { float f; unsigned int i; } v; v.f = f;
    unsigned int r = v.i + 0x7fffu + ((v.i >> 16) & 1u);
    return (u16)(r >> 16);
}
DEV float bdec(u16 u) {
    union { unsigned int i; float f; } v; v.i = ((unsigned int)u) << 16; return v.f;
}

DEV f32x4 MFMA(bf16x8 a, bf16x8 b, f32x4 c) {
    return __builtin_amdgcn_mfma_f32_16x16x32_bf16(a, b, c, 0, 0, 0);
}
DEV f32x16 MFMA32(bf16x8 a, bf16x8 b, f32x16 c) {
    return __builtin_amdgcn_mfma_f32_32x32x16_bf16(a, b, c, 0, 0, 0);
}
DEV f32x16 zero16() {
    f32x16 z;
    #pragma unroll
    for (int i = 0; i < 16; i++) z[i] = 0.f;
    return z;
}

// ---------------- transpose fp32 [R][C] -> bf16 [C][R] ----------------
__global__ __launch_bounds__(256)
void k_transpose(const float* __restrict__ in, u16* __restrict__ out, int R, int C) {
    __shared__ float tile[32][33];
    int c0 = blockIdx.x * 32, r0 = blockIdx.y * 32;
    int tx = threadIdx.x, ty = threadIdx.y; // 32 x 8
    #pragma unroll
    for (int i = 0; i < 32; i += 8)
        tile[ty + i][tx] = in[(size_t)(r0 + ty + i) * C + c0 + tx];
    __syncthreads();
    #pragma unroll
    for (int i = 0; i < 32; i += 8)
        out[(size_t)(c0 + ty + i) * R + r0 + tx] = f2bf(tile[tx][ty + i]);
}

// ------------- bf16 V transpose: qkv v-cols [s][d] -> vT[bh][d][s] -------------
__global__ __launch_bounds__(256)
void k_transpose_v(const u16* __restrict__ qkv, u16* __restrict__ vT) {
    __shared__ u16 tile[32][33];
    int bid = blockIdx.x;
    int st = bid & 63;           // s tile (2048/32)
    int dt = (bid >> 6) & 1;     // d tile (64/32)
    int bh = bid >> 7;           // 0..31
    int b = bh >> 4, h = bh & 15;
    int s0 = st * 32, d0 = dt * 32;
    int tx = threadIdx.x & 31, ty = threadIdx.x >> 5;   // 32 x 8
    const u16* src = qkv + ((size_t)(b * SS + s0)) * NQKV + 2048 + h * DH + d0;
    #pragma unroll
    for (int i = 0; i < 32; i += 8)
        tile[ty + i][tx] = src[(size_t)(ty + i) * NQKV + tx];
    __syncthreads();
    u16* dst = vT + ((size_t)bh * DH + d0) * SS + s0;
    #pragma unroll
    for (int i = 0; i < 32; i += 8)
        dst[(size_t)(ty + i) * SS + tx] = tile[tx][ty + i];
}

// ---------------- layernorm fp32 -> bf16, one block per row ----------------
__global__ __launch_bounds__(256)
void k_layernorm(const float* __restrict__ x, const float* __restrict__ g,
                 const float* __restrict__ b, u16* __restrict__ out) {
    int row = blockIdx.x, t = threadIdx.x;
    const float4* xp = reinterpret_cast<const float4*>(x + (size_t)row * DD);
    float4 v = xp[t];
    float s = v.x + v.y + v.z + v.w;
    float q = v.x * v.x + v.y * v.y + v.z * v.z + v.w * v.w;
    #pragma unroll
    for (int m = 1; m < 64; m <<= 1) { s += __shfl_xor(s, m); q += __shfl_xor(q, m); }
    __shared__ float ps[4], pq[4];
    int w = t >> 6, l = t & 63;
    if (l == 0) { ps[w] = s; pq[w] = q; }
    __syncthreads();
    s = ps[0] + ps[1] + ps[2] + ps[3];
    q = pq[0] + pq[1] + pq[2] + pq[3];
    float mu = s * (1.0f / DD);
    float var = q * (1.0f / DD) - mu * mu;
    float rstd = rsqrtf(var + 1e-5f);
    float4 gv = reinterpret_cast<const float4*>(g)[t];
    float4 bv = reinterpret_cast<const float4*>(b)[t];
    u16x4 o;
    o.x = f2bf((v.x - mu) * rstd * gv.x + bv.x);
    o.y = f2bf((v.y - mu) * rstd * gv.y + bv.y);
    o.z = f2bf((v.z - mu) * rstd * gv.z + bv.z);
    o.w = f2bf((v.w - mu) * rstd * gv.w + bv.w);
    reinterpret_cast<u16x4*>(out + (size_t)row * DD)[t] = o;
}

// -------- fused split-K reduce + LN: X1 = x+P0+P1+bias; LNout = LN(X1) --------
__global__ __launch_bounds__(256)
void k_redln(const float* __restrict__ x, const u16* __restrict__ P0,
             const u16* __restrict__ P1, const float* __restrict__ bias,
             const float* __restrict__ g, const float* __restrict__ be,
             float* __restrict__ X1, u16* __restrict__ LNout) {
    int row = blockIdx.x, t = threadIdx.x;
    size_t i = (size_t)row * 256 + t;
    float4 xv = reinterpret_cast<const float4*>(x)[i];
    u16x4 a = reinterpret_cast<const u16x4*>(P0)[i];
    u16x4 bb = reinterpret_cast<const u16x4*>(P1)[i];
    float4 bv = reinterpret_cast<const float4*>(bias)[t];
    float4 v;
    v.x = xv.x + bdec(a.x) + bdec(bb.x) + bv.x;
    v.y = xv.y + bdec(a.y) + bdec(bb.y) + bv.y;
    v.z = xv.z + bdec(a.z) + bdec(bb.z) + bv.z;
    v.w = xv.w + bdec(a.w) + bdec(bb.w) + bv.w;
    reinterpret_cast<float4*>(X1)[i] = v;
    float s = v.x + v.y + v.z + v.w;
    float q = v.x * v.x + v.y * v.y + v.z * v.z + v.w * v.w;
    #pragma unroll
    for (int m = 1; m < 64; m <<= 1) { s += __shfl_xor(s, m); q += __shfl_xor(q, m); }
    __shared__ float ps[4], pq[4];
    int w = t >> 6, l = t & 63;
    if (l == 0) { ps[w] = s; pq[w] = q; }
    __syncthreads();
    s = ps[0] + ps[1] + ps[2] + ps[3];
    q = pq[0] + pq[1] + pq[2] + pq[3];
    float mu = s * (1.0f / DD);
    float var = q * (1.0f / DD) - mu * mu;
    float rstd = rsqrtf(var + 1e-5f);
    float4 gv = reinterpret_cast<const float4*>(g)[t];
    float4 ev = reinterpret_cast<const float4*>(be)[t];
    u16x4 o;
    o.x = f2bf((v.x - mu) * rstd * gv.x + ev.x);
    o.y = f2bf((v.y - mu) * rstd * gv.y + ev.y);
    o.z = f2bf((v.z - mu) * rstd * gv.z + ev.z);
    o.w = f2bf((v.w - mu) * rstd * gv.w + ev.w);
    reinterpret_cast<u16x4*>(LNout + (size_t)row * DD)[t] = o;
}

// --------- qkv GEMM: 128x128, 2-phase counted-vmcnt (proven r10 path) ---------
// Cb[m][n] = A@BT^T; q cols (<1024) pre-scaled by 0.125*log2e; linear store.
__global__ __launch_bounds__(256)
void k_gemm_qkv(const u16* __restrict__ A, const u16* __restrict__ BT,
                u16* __restrict__ Cb, int M, int N, int K) {
    __shared__ __align__(128) char lds[2][32768];
    const int t = threadIdx.x;
    const int w = t >> 6, l = t & 63;
    const int lg = l >> 4, lr = l & 15;
    const int m0 = blockIdx.y * 128, n0 = blockIdx.x * 128;
    const int wr = w >> 1, wc = w & 1;

    const int csw = ((l & 7) ^ (l >> 3)) << 3;
    const int chunk0 = w * 4;
    const int srow = (l >> 3);

    f32x4 acc[4][4];
    #pragma unroll
    for (int i = 0; i < 4; i++)
        #pragma unroll
        for (int j = 0; j < 4; j++)
            acc[i][j] = (f32x4){0.f, 0.f, 0.f, 0.f};

    #pragma unroll
    for (int i = 0; i < 4; i++) {
        const int chunk = chunk0 + i;
        const int r = chunk * 8 + srow;
        __builtin_amdgcn_global_load_lds(GLD_AS1(A  + (size_t)(m0 + r) * K + csw),
                                         GLD_AS3(lds[0] + chunk * 1024), 16, 0, 0);
        __builtin_amdgcn_global_load_lds(GLD_AS1(BT + (size_t)(n0 + r) * K + csw),
                                         GLD_AS3(lds[0] + 16384 + chunk * 1024), 16, 0, 0);
    }

    int buf = 0;
    for (int kt = 0; kt < K; kt += 64) {
        if (kt + 64 < K) {
            #pragma unroll
            for (int i = 0; i < 4; i++) {
                const int chunk = chunk0 + i;
                const int r = chunk * 8 + srow;
                __builtin_amdgcn_global_load_lds(GLD_AS1(A  + (size_t)(m0 + r) * K + kt + 64 + csw),
                                                 GLD_AS3(lds[buf ^ 1] + chunk * 1024), 16, 0, 0);
                __builtin_amdgcn_global_load_lds(GLD_AS1(BT + (size_t)(n0 + r) * K + kt + 64 + csw),
                                                 GLD_AS3(lds[buf ^ 1] + 16384 + chunk * 1024), 16, 0, 0);
            }
            WAIT_BAR(8);
        } else {
            WAIT_BAR(0);
        }
        const char* Al = lds[buf];
        const char* Bl = lds[buf] + 16384;
        #pragma unroll
        for (int s = 0; s < 2; s++) {
            const int swz = (s * 64 + lg * 16) ^ ((lr & 7) << 4);
            bf16x8 af[4], bfr[4];
            #pragma unroll
            for (int mi = 0; mi < 4; mi++)
                af[mi] = *reinterpret_cast<const bf16x8*>(Al + (wr * 64 + mi * 16 + lr) * 128 + swz);
            #pragma unroll
            for (int ni = 0; ni < 4; ni++)
                bfr[ni] = *reinterpret_cast<const bf16x8*>(Bl + (wc * 64 + ni * 16 + lr) * 128 + swz);
            #pragma unroll
            for (int mi = 0; mi < 4; mi++)
                #pragma unroll
                for (int ni = 0; ni < 4; ni++)
                    acc[mi][ni] = MFMA(af[mi], bfr[ni], acc[mi][ni]);
        }
        BAR();
        buf ^= 1;
    }

    #pragma unroll
    for (int mi = 0; mi < 4; mi++) {
        #pragma unroll
        for (int ni = 0; ni < 4; ni++) {
            int nn = n0 + wc * 64 + ni * 16 + lr;
            #pragma unroll
            for (int r = 0; r < 4; r++) {
                int mm = m0 + wr * 64 + mi * 16 + lg * 4 + r;
                float v = acc[mi][ni][r];
                float sv = (nn < 1024) ? v * 0.18033688011112042f : v;
                Cb[(size_t)mm * NQKV + nn] = f2bf(sv);
            }
        }
    }
}

// ---- ff1 GEMM: 256x256, fine-grained 4-phase/tile, counted vmcnt, setprio ----
// 8 waves (2x4). Per K-tile t: phase p stages half-tile p of t+1 (2 loads/thr)
// into buf^1, reads A-quadrant p frags (+B frags at p0) from buf, 16 MFMA.
// One counted wait/tile: at p0 after issuing h0(t+1), vmcnt(2) -> tile t's 4
// halves (older than newest 2 loads) are landed; h0(t+1) stays in flight.
// Epilogue: tanh-GELU + bias.
__global__ __launch_bounds__(512, 2)
void k_gemm_ff1(const u16* __restrict__ A, const u16* __restrict__ BT,
                u16* __restrict__ Cb, const float* __restrict__ bias,
                int M, int N, int K) {
    __shared__ __align__(128) char lds[2][65536];   // per buf: A h0,h1 | B h0,h1 (16KB each)
    const int t = threadIdx.x;
    const int w = t >> 6, l = t & 63;
    const int lg = l >> 4, lr = l & 15;
    const int m0 = blockIdx.y * 256, n0 = blockIdx.x * 256;
    const int wr = w >> 2, wc = w & 3;

    const int csw = ((l & 7) ^ (l >> 3)) << 3;   // pre-swizzled source col (elems)
    const int srow8 = l >> 3;
    const int swzc = (lr & 7) << 4;              // read-side byte xor

    f32x4 acc[8][4];
    #pragma unroll
    for (int i = 0; i < 8; i++)
        #pragma unroll
        for (int j = 0; j < 4; j++)
            acc[i][j] = (f32x4){0.f, 0.f, 0.f, 0.f};

    // stage one 16KB half: which=0 -> A rows, 1 -> B rows; half in {0,1}; 2 loads/thread
    auto STAGEH = [&](int bf, int which, int half, int kt) {
        const u16* sb = which ? BT : A;
        const int rb = which ? n0 : m0;
        char* dst = lds[bf] + which * 32768 + half * 16384 + w * 1024;
        #pragma unroll
        for (int j = 0; j < 2; j++) {
            const int r = half * 128 + (j * 8 + w) * 8 + srow8;
            __builtin_amdgcn_global_load_lds(GLD_AS1(sb + (size_t)(rb + r) * K + kt + csw),
                                             GLD_AS3(dst + j * 8192), 16, 0, 0);
        }
    };

    // prologue: tile 0's 4 halves into buf 0 (8 loads/thread)
    STAGEH(0, 0, 0, 0); STAGEH(0, 0, 1, 0); STAGEH(0, 1, 0, 0); STAGEH(0, 1, 1, 0);

    const int nt = K >> 6;
    int buf = 0;
    for (int tt = 0; tt < nt; ++tt) {
        const int nb = buf ^ 1;
        const bool pre = (tt + 1 < nt);
        const char* Abase = lds[buf];
        const char* Bbase = lds[buf] + 32768;

        bf16x8 Bf[4][2];
        #pragma unroll
        for (int p = 0; p < 4; p++) {
            // stage half p of tile t+1
            if (pre) STAGEH(nb, p >> 1, p & 1, (tt + 1) * 64);
            if (p == 0) {
                if (pre) { WAIT_BAR(2); } else { WAIT_BAR(0); }
                // B fragments: all 4 n-frags x 2 k-steps (reused all phases)
                #pragma unroll
                for (int ni = 0; ni < 4; ni++)
                    #pragma unroll
                    for (int ks = 0; ks < 2; ks++)
                        Bf[ni][ks] = *reinterpret_cast<const bf16x8*>(
                            Bbase + (wc >> 1) * 16384 + ((wc & 1) * 64 + ni * 16 + lr) * 128
                                  + ((ks * 64 + lg * 16) ^ swzc));
            }
            // A quadrant p fragments
            bf16x8 Af[2][2];
            #pragma unroll
            for (int mi2 = 0; mi2 < 2; mi2++)
                #pragma unroll
                for (int ks = 0; ks < 2; ks++)
                    Af[mi2][ks] = *reinterpret_cast<const bf16x8*>(
                        Abase + wr * 16384 + ((p * 2 + mi2) * 16 + lr) * 128
                              + ((ks * 64 + lg * 16) ^ swzc));
            __builtin_amdgcn_s_setprio(1);
            #pragma unroll
            for (int mi2 = 0; mi2 < 2; mi2++)
                #pragma unroll
                for (int ni = 0; ni < 4; ni++)
                    #pragma unroll
                    for (int ks = 0; ks < 2; ks++)
                        acc[p * 2 + mi2][ni] = MFMA(Af[mi2][ks], Bf[ni][ks], acc[p * 2 + mi2][ni]);
            __builtin_amdgcn_s_setprio(0);
            BAR();
        }
        buf = nb;
    }

    // epilogue: tanh-GELU + bias
    #pragma unroll
    for (int mi = 0; mi < 8; mi++) {
        #pragma unroll
        for (int ni = 0; ni < 4; ni++) {
            int nn = n0 + wc * 64 + ni * 16 + lr;
            #pragma unroll
            for (int r = 0; r < 4; r++) {
                int mm = m0 + wr * 128 + mi * 16 + lg * 4 + r;
                float u = acc[mi][ni][r] + bias[nn];
                float u3 = u * u * u;
                float gl = u / (1.0f + exp2f(-2.3022077f * u - 0.10294276f * u3));
                Cb[(size_t)mm * N + nn] = f2bf(gl);
            }
        }
    }
}

// ---------------- 128x128 GEMM (split-K partials), 2-phase pipeline ----------
__global__ __launch_bounds__(256)
void k_gemm_sk(const u16* __restrict__ A, const u16* __restrict__ BT,
               u16* __restrict__ P0, u16* __restrict__ P1, int M, int N, int K) {
    __shared__ __align__(128) char lds[2][32768];
    const int t = threadIdx.x;
    const int w = t >> 6, l = t & 63;
    const int lg = l >> 4, lr = l & 15;
    const int m0 = blockIdx.y * 128, n0 = blockIdx.x * 128;
    const int wr = w >> 1, wc = w & 1;

    const int kh = K >> 1;
    const int kbeg = blockIdx.z * kh;
    const int kend = kbeg + kh;

    const int csw = ((l & 7) ^ (l >> 3)) << 3;
    const int chunk0 = w * 4;
    const int srow = (l >> 3);

    f32x4 acc[4][4];
    #pragma unroll
    for (int i = 0; i < 4; i++)
        #pragma unroll
        for (int j = 0; j < 4; j++)
            acc[i][j] = (f32x4){0.f, 0.f, 0.f, 0.f};

    #pragma unroll
    for (int i = 0; i < 4; i++) {
        const int chunk = chunk0 + i;
        const int r = chunk * 8 + srow;
        __builtin_amdgcn_global_load_lds(GLD_AS1(A  + (size_t)(m0 + r) * K + kbeg + csw),
                                         GLD_AS3(lds[0] + chunk * 1024), 16, 0, 0);
        __builtin_amdgcn_global_load_lds(GLD_AS1(BT + (size_t)(n0 + r) * K + kbeg + csw),
                                         GLD_AS3(lds[0] + 16384 + chunk * 1024), 16, 0, 0);
    }

    int buf = 0;
    for (int kt = kbeg; kt < kend; kt += 64) {
        if (kt + 64 < kend) {
            #pragma unroll
            for (int i = 0; i < 4; i++) {
                const int chunk = chunk0 + i;
                const int r = chunk * 8 + srow;
                __builtin_amdgcn_global_load_lds(GLD_AS1(A  + (size_t)(m0 + r) * K + kt + 64 + csw),
                                                 GLD_AS3(lds[buf ^ 1] + chunk * 1024), 16, 0, 0);
                __builtin_amdgcn_global_load_lds(GLD_AS1(BT + (size_t)(n0 + r) * K + kt + 64 + csw),
                                                 GLD_AS3(lds[buf ^ 1] + 16384 + chunk * 1024), 16, 0, 0);
            }
            WAIT_BAR(8);
        } else {
            WAIT_BAR(0);
        }
        const char* Al = lds[buf];
        const char* Bl = lds[buf] + 16384;
        #pragma unroll
        for (int s = 0; s < 2; s++) {
            const int swz = (s * 64 + lg * 16) ^ ((lr & 7) << 4);
            bf16x8 af[4], bfr[4];
            #pragma unroll
            for (int mi = 0; mi < 4; mi++)
                af[mi] = *reinterpret_cast<const bf16x8*>(Al + (wr * 64 + mi * 16 + lr) * 128 + swz);
            #pragma unroll
            for (int ni = 0; ni < 4; ni++)
                bfr[ni] = *reinterpret_cast<const bf16x8*>(Bl + (wc * 64 + ni * 16 + lr) * 128 + swz);
            #pragma unroll
            for (int mi = 0; mi < 4; mi++)
                #pragma unroll
                for (int ni = 0; ni < 4; ni++)
                    acc[mi][ni] = MFMA(af[mi], bfr[ni], acc[mi][ni]);
        }
        BAR();
        buf ^= 1;
    }

    u16* dst = blockIdx.z ? P1 : P0;
    #pragma unroll
    for (int mi = 0; mi < 4; mi++) {
        #pragma unroll
        for (int ni = 0; ni < 4; ni++) {
            int nn = n0 + wc * 64 + ni * 16 + lr;
            #pragma unroll
            for (int r = 0; r < 4; r++) {
                int mm = m0 + wr * 64 + mi * 16 + lg * 4 + r;
                dst[(size_t)mm * N + nn] = f2bf(acc[mi][ni][r]);
            }
        }
    }
}

// ------------- final split-K reduce: OUT = RES + P0 + P1 + bias ---------------
__global__ __launch_bounds__(256)
void k_ffreduce(const float* __restrict__ RES, const u16* __restrict__ P0,
                const u16* __restrict__ P1, const float* __restrict__ bias,
                float* __restrict__ OUT) {
    int i = blockIdx.x * 256 + threadIdx.x;      // float4 index
    float4 xv = reinterpret_cast<const float4*>(RES)[i];
    u16x4 a = reinterpret_cast<const u16x4*>(P0)[i];
    u16x4 b = reinterpret_cast<const u16x4*>(P1)[i];
    float4 bv = reinterpret_cast<const float4*>(bias)[i & (DD / 4 - 1)];
    float4 o;
    o.x = xv.x + bdec(a.x) + bdec(b.x) + bv.x;
    o.y = xv.y + bdec(a.y) + bdec(b.y) + bv.y;
    o.z = xv.z + bdec(a.z) + bdec(b.z) + bv.z;
    o.w = xv.w + bdec(a.w) + bdec(b.w) + bv.w;
    reinterpret_cast<float4*>(OUT)[i] = o;
}

// ------- flash attention, swapped-QK 32x32, KVBLK=64, cross-iter pipeline ------
__global__ __launch_bounds__(256)
void k_attn(const u16* __restrict__ qkv, const u16* __restrict__ vT,
            u16* __restrict__ out) {
    const int w = threadIdx.x >> 6, l = threadIdx.x & 63;
    const int q = l & 31, hi = l >> 5;
    const int task = (blockIdx.x & 7) * 64 + (blockIdx.x >> 3);  // 512-block bijection
    const int bh = task >> 4;                // 0..31 (4 heads per XCD)
    const int qg = task & 15;
    const int b = bh >> 4, h = bh & 15;
    const size_t rowbase = (size_t)b * SS;
    const int q0 = (qg * 4 + w) * 32;

    __shared__ __align__(128) u16 Kl[3][64 * 64];   // triple buffer (stage depth 2)
    __shared__ __align__(128) u16 Vl[2][64 * 64];   // double buffer

    const u16* kbase = qkv + rowbase * NQKV + 1024 + h * DH;
    const u16* vbase = vT + (size_t)bh * DH * SS;

    const int srow8 = l >> 3;
    const int sslot = (l & 7) ^ srow8;
    const int kr0 = w * 8 + srow8;
    const u16* kg0 = kbase + (size_t)kr0 * NQKV + sslot * 8;
    const u16* kg1 = kbase + (size_t)(kr0 + 32) * NQKV + sslot * 8;
    const u16* vg0 = vbase + (size_t)kr0 * SS + sslot * 8;
    const u16* vg1 = vbase + (size_t)(kr0 + 32) * SS + sslot * 8;
    const int chA = (w * 8) * 64, chB = (w * 8 + 32) * 64;

    const u16* qrow = qkv + (rowbase + q0 + q) * NQKV + h * DH + hi * 8;
    bf16x8 qf[4];
    #pragma unroll
    for (int ks = 0; ks < 4; ks++)
        qf[ks] = *reinterpret_cast<const bf16x8*>(qrow + ks * 16);
    asm volatile("s_waitcnt vmcnt(0)" ::: "memory");

    bf16x8 onesf;
    #pragma unroll
    for (int i = 0; i < 8; i++) onesf[i] = (__bf16)1.0f;

    f32x16 o0 = zero16(), o1 = zero16();
    f32x16 lacc = zero16();
    const int qsw = (q & 7) << 3;

    __builtin_amdgcn_global_load_lds(GLD_AS1(kg0), GLD_AS3((u16*)Kl[0] + chA), 16, 0, 0);
    __builtin_amdgcn_global_load_lds(GLD_AS1(kg1), GLD_AS3((u16*)Kl[0] + chB), 16, 0, 0);
    __builtin_amdgcn_global_load_lds(GLD_AS1(kg0 + (size_t)64 * NQKV), GLD_AS3((u16*)Kl[1] + chA), 16, 0, 0);
    __builtin_amdgcn_global_load_lds(GLD_AS1(kg1 + (size_t)64 * NQKV), GLD_AS3((u16*)Kl[1] + chB), 16, 0, 0);
    __builtin_amdgcn_global_load_lds(GLD_AS1(vg0), GLD_AS3((u16*)Vl[0] + chA), 16, 0, 0);
    __builtin_amdgcn_global_load_lds(GLD_AS1(vg1), GLD_AS3((u16*)Vl[0] + chB), 16, 0, 0);
    WAIT_BAR(4);

    f32x16 scA0 = zero16(), scA1 = zero16();
    {
        const u16* Kb = Kl[0];
        #pragma unroll
        for (int ks = 0; ks < 4; ks++) {
            const int off = (ks * 16 + hi * 8) ^ qsw;
            bf16x8 kf0 = *reinterpret_cast<const bf16x8*>(Kb + q * 64 + off);
            bf16x8 kf1 = *reinterpret_cast<const bf16x8*>(Kb + (q + 32) * 64 + off);
            scA0 = MFMA32(kf0, qf[ks], scA0);
            scA1 = MFMA32(kf1, qf[ks], scA1);
        }
    }

    int kRead = 1, vRead = 0;
    for (int i = 0; i < 32; ++i) {
        const int kStage = (kRead == 2) ? 0 : kRead + 1;
        if (i + 2 < 32) {
            const size_t koff = (size_t)(i + 2) * 64 * NQKV;
            __builtin_amdgcn_global_load_lds(GLD_AS1(kg0 + koff), GLD_AS3((u16*)Kl[kStage] + chA), 16, 0, 0);
            __builtin_amdgcn_global_load_lds(GLD_AS1(kg1 + koff), GLD_AS3((u16*)Kl[kStage] + chB), 16, 0, 0);
            WAIT_BAR(2);
        } else {
            WAIT_BAR(0);
        }
        if (i + 1 < 32) {
            const int voff = (i + 1) * 64;
            __builtin_amdgcn_global_load_lds(GLD_AS1(vg0 + voff), GLD_AS3((u16*)Vl[vRead ^ 1] + chA), 16, 0, 0);
            __builtin_amdgcn_global_load_lds(GLD_AS1(vg1 + voff), GLD_AS3((u16*)Vl[vRead ^ 1] + chB), 16, 0, 0);
        }

        f32x16 p0, p1;
        #pragma unroll
        for (int j = 0; j < 16; j++) p0[j] = exp2f(scA0[j]);
        #pragma unroll
        for (int j = 0; j < 16; j++) p1[j] = exp2f(scA1[j]);

        f32x16 stB0 = zero16(), stB1 = zero16();
        if (i + 1 < 32) {
            const u16* Kb = Kl[kRead];
            #pragma unroll
            for (int ks = 0; ks < 4; ks++) {
                const int off = (ks * 16 + hi * 8) ^ qsw;
                bf16x8 kf0 = *reinterpret_cast<const bf16x8*>(Kb + q * 64 + off);
                bf16x8 kf1 = *reinterpret_cast<const bf16x8*>(Kb + (q + 32) * 64 + off);
                stB0 = MFMA32(kf0, qf[ks], stB0);
                stB1 = MFMA32(kf1, qf[ks], stB1);
            }
        }

        union W { unsigned int u; __bf16 h[2]; };
        W pw[16];
        #pragma unroll
        for (int m = 0; m < 8; m++) {
            pw[m].h[0] = (__bf16)p0[2 * m];
            pw[m].h[1] = (__bf16)p0[2 * m + 1];
            pw[8 + m].h[0] = (__bf16)p1[2 * m];
            pw[8 + m].h[1] = (__bf16)p1[2 * m + 1];
        }
        bf16x8 pf[4];
        #pragma unroll
        for (int kk = 0; kk < 4; kk++) {
            const int base = (kk >> 1) * 8 + (kk & 1) * 4;
            unsigned int a0 = pw[base + 0].u, a1 = pw[base + 1].u;
            unsigned int b0 = pw[base + 2].u, b1 = pw[base + 3].u;
            unsigned int own0 = hi ? b0 : a0, own1 = hi ? b1 : a1;
            unsigned int snd0 = hi ? a0 : b0, snd1 = hi ? a1 : b1;
            unsigned int r0 = __shfl_xor(snd0, 32), r1 = __shfl_xor(snd1, 32);
            union F { unsigned int u[4]; bf16x8 v; } f;
            f.u[0] = hi ? r0 : own0;
            f.u[1] = hi ? r1 : own1;
            f.u[2] = hi ? own0 : r0;
            f.u[3] = hi ? own1 : r1;
            pf[kk] = f.v;
        }

        const u16* Vb = Vl[vRead];
        #pragma unroll
        for (int kk = 0; kk < 4; kk++) {
            const int off = (kk * 16 + hi * 8) ^ qsw;
            bf16x8 v0 = *reinterpret_cast<const bf16x8*>(Vb + q * 64 + off);
            bf16x8 v1 = *reinterpret_cast<const bf16x8*>(Vb + (q + 32) * 64 + off);
            lacc = MFMA32(onesf, pf[kk], lacc);
            o0 = MFMA32(v0, pf[kk], o0);
            o1 = MFMA32(v1, pf[kk], o1);
        }

        scA0 = stB0;
        scA1 = stB1;
        kRead = kStage;
        vRead ^= 1;
    }

    float invl = 1.0f / lacc[0];
    u16* orow = out + (rowbase + q0 + q) * DD + h * DH + hi * 4;
    #pragma unroll
    for (int a = 0; a < 4; a++) {
        u16x4 s0v, s1v;
        #pragma unroll
        for (int i = 0; i < 4; i++) {
            s0v[i] = f2bf(o0[4 * a + i] * invl);
            s1v[i] = f2bf(o1[4 * a + i] * invl);
        }
        *reinterpret_cast<u16x4*>(orow + 8 * a)      = s0v;
        *reinterpret_cast<u16x4*>(orow + 32 + 8 * a) = s1v;
    }
}

extern "C" void kernel_launch(void* const* d_in, const int* in_sizes, int n_in,
                              void* d_out, int out_size, void* d_ws, size_t ws_size,
                              hipStream_t stream) {
    (void)in_sizes; (void)n_in; (void)out_size; (void)ws_size;
    const float* x     = (const float*)d_in[0];
    const float* w_qkv = (const float*)d_in[1];
    const float* w_out = (const float*)d_in[2];
    const float* b_out = (const float*)d_in[3];
    const float* g1    = (const float*)d_in[4];
    const float* be1   = (const float*)d_in[5];
    const float* g2    = (const float*)d_in[6];
    const float* be2   = (const float*)d_in[7];
    const float* w_ff1 = (const float*)d_in[8];
    const float* b_ff1 = (const float*)d_in[9];
    const float* w_ff2 = (const float*)d_in[10];
    const float* b_ff2 = (const float*)d_in[11];

    char* ws = (char*)d_ws;
    u16*   W  = (u16*)(ws);                  //  8.39 MB  (weight^T scratch, reused)
    u16*   Hb = (u16*)(ws + 8388608);        //  8.39 MB  (LN1 out; later partials)
    u16*   QF = (u16*)(ws + 16777216);       // 33.55 MB  (qkv, later ffn act)
    u16*   VT = (u16*)(ws + 50331648);       //  8.39 MB  (v^T; later partials)
    u16*   AO = (u16*)(ws + 58720256);       //  8.39 MB  (attn out; later LN2 out)
    float* X1 = (float*)(ws + 67108864);     // 16.78 MB  (post-attn residual fp32)
    float* OUT = (float*)d_out;

    // LN1: x -> Hb
    k_layernorm<<<NTOK, 256, 0, stream>>>(x, g1, be1, Hb);
    // w_qkv^T
    k_transpose<<<dim3(3072 / 32, 1024 / 32), dim3(32, 8), 0, stream>>>(w_qkv, W, 1024, 3072);
    // qkv = Hb @ w_qkv  (128^2 2-phase; q cols pre-scaled; linear store)
    k_gemm_qkv<<<dim3(3072 / 128, 4096 / 128), 256, 0, stream>>>(
        Hb, W, QF, NTOK, NQKV, 1024);
    // V transpose (coalesced both sides)
    k_transpose_v<<<4096, 256, 0, stream>>>(QF, VT);
    // attention (512 blocks, XCD-swizzled, KVBLK=64, cross-iter pipelined)
    k_attn<<<512, 256, 0, stream>>>(QF, VT, AO);
    // w_out^T
    k_transpose<<<dim3(1024 / 32, 1024 / 32), dim3(32, 8), 0, stream>>>(w_out, W, 1024, 1024);
    // attn-out split-K x2: partials P0 -> Hb, P1 -> VT
    k_gemm_sk<<<dim3(1024 / 128, 4096 / 128, 2), 256, 0, stream>>>(
        AO, W, Hb, VT, NTOK, 1024, 1024);
    // fused: X1 = x + P0 + P1 + b_out ; AO = LN2(X1)
    k_redln<<<NTOK, 256, 0, stream>>>(x, Hb, VT, b_out, g2, be2, X1, AO);
    // w_ff1^T
    k_transpose<<<dim3(4096 / 32, 1024 / 32), dim3(32, 8), 0, stream>>>(w_ff1, W, 1024, 4096);
    // FFA = gelu(AO @ w_ff1 + b_ff1) -> QF   (256^2 fine-grained 4-phase)
    k_gemm_ff1<<<dim3(4096 / 256, 4096 / 256), 512, 0, stream>>>(
        AO, W, QF, b_ff1, NTOK, 4096, 1024);
    // w_ff2^T
    k_transpose<<<dim3(1024 / 32, 4096 / 32), dim3(32, 8), 0, stream>>>(w_ff2, W, 4096, 1024);
    // ff2 split-K x2: partials P0 -> VT, P1 -> Hb
    k_gemm_sk<<<dim3(1024 / 128, 4096 / 128, 2), 256, 0, stream>>>(
        QF, W, VT, Hb, NTOK, 1024, 4096);
    // OUT = X1 + P0 + P1 + b_ff2
    k_ffreduce<<<NTOK * DD / 4 / 256, 256, 0, stream>>>(X1, VT, Hb, b_ff2, OUT);
}

// Round 13
// 252.247 us; speedup vs baseline: 1.0397x; 1.0047x over previous
//
#include <hip/hip_runtime.h>
#include <math.h>

typedef unsigned short u16;
typedef __attribute__((ext_vector_type(4))) float f32x4;
typedef __attribute__((ext_vector_type(16))) float f32x16;
typedef __attribute__((ext_vector_type(4))) unsigned short u16x4;
typedef __attribute__((ext_vector_type(8))) __bf16 bf16x8;

static constexpr int SS   = 2048;   // seq len
static constexpr int DD   = 1024;   // model dim
static constexpr int HH   = 16;     // heads
static constexpr int DH   = 64;     // head dim
static constexpr int NTOK = 4096;   // B*S
static constexpr int NQKV = 3072;

#define DEV static __device__ __forceinline__
#define GLD_AS1(p) ((__attribute__((address_space(1))) void*)(void*)(p))
#define GLD_AS3(p) ((__attribute__((address_space(3))) void*)(p))

// fused counted-wait + barrier (T4)
#define WAIT_BAR(N) asm volatile("s_waitcnt vmcnt(" #N ")\n\ts_barrier" ::: "memory")
#define BAR()       asm volatile("s_barrier" ::: "memory")

DEV u16 f2bf(float f) {
    union { float f; unsigned int i; } v; v.f = f;
    unsigned int r = v.i + 0x7fffu + ((v.i >> 16) & 1u);
    return (u16)(r >> 16);
}
DEV float bdec(u16 u) {
    union { unsigned int i; float f; } v; v.i = ((unsigned int)u) << 16; return v.f;
}

DEV f32x4 MFMA(bf16x8 a, bf16x8 b, f32x4 c) {
    return __builtin_amdgcn_mfma_f32_16x16x32_bf16(a, b, c, 0, 0, 0);
}
DEV f32x16 MFMA32(bf16x8 a, bf16x8 b, f32x16 c) {
    return __builtin_amdgcn_mfma_f32_32x32x16_bf16(a, b, c, 0, 0, 0);
}
DEV f32x16 zero16() {
    f32x16 z;
    #pragma unroll
    for (int i = 0; i < 16; i++) z[i] = 0.f;
    return z;
}

// ---------------- transpose fp32 [R][C] -> bf16 [C][R] ----------------
__global__ __launch_bounds__(256)
void k_transpose(const float* __restrict__ in, u16* __restrict__ out, int R, int C) {
    __shared__ float tile[32][33];
    int c0 = blockIdx.x * 32, r0 = blockIdx.y * 32;
    int tx = threadIdx.x, ty = threadIdx.y; // 32 x 8
    #pragma unroll
    for (int i = 0; i < 32; i += 8)
        tile[ty + i][tx] = in[(size_t)(r0 + ty + i) * C + c0 + tx];
    __syncthreads();
    #pragma unroll
    for (int i = 0; i < 32; i += 8)
        out[(size_t)(c0 + ty + i) * R + r0 + tx] = f2bf(tile[tx][ty + i]);
}

// ------------- bf16 V transpose: qkv v-cols [s][d] -> vT[bh][d][s] -------------
__global__ __launch_bounds__(256)
void k_transpose_v(const u16* __restrict__ qkv, u16* __restrict__ vT) {
    __shared__ u16 tile[32][33];
    int bid = blockIdx.x;
    int st = bid & 63;           // s tile (2048/32)
    int dt = (bid >> 6) & 1;     // d tile (64/32)
    int bh = bid >> 7;           // 0..31
    int b = bh >> 4, h = bh & 15;
    int s0 = st * 32, d0 = dt * 32;
    int tx = threadIdx.x & 31, ty = threadIdx.x >> 5;   // 32 x 8
    const u16* src = qkv + ((size_t)(b * SS + s0)) * NQKV + 2048 + h * DH + d0;
    #pragma unroll
    for (int i = 0; i < 32; i += 8)
        tile[ty + i][tx] = src[(size_t)(ty + i) * NQKV + tx];
    __syncthreads();
    u16* dst = vT + ((size_t)bh * DH + d0) * SS + s0;
    #pragma unroll
    for (int i = 0; i < 32; i += 8)
        dst[(size_t)(ty + i) * SS + tx] = tile[tx][ty + i];
}

// ---------------- layernorm fp32 -> bf16, one block per row ----------------
__global__ __launch_bounds__(256)
void k_layernorm(const float* __restrict__ x, const float* __restrict__ g,
                 const float* __restrict__ b, u16* __restrict__ out) {
    int row = blockIdx.x, t = threadIdx.x;
    const float4* xp = reinterpret_cast<const float4*>(x + (size_t)row * DD);
    float4 v = xp[t];
    float s = v.x + v.y + v.z + v.w;
    float q = v.x * v.x + v.y * v.y + v.z * v.z + v.w * v.w;
    #pragma unroll
    for (int m = 1; m < 64; m <<= 1) { s += __shfl_xor(s, m); q += __shfl_xor(q, m); }
    __shared__ float ps[4], pq[4];
    int w = t >> 6, l = t & 63;
    if (l == 0) { ps[w] = s; pq[w] = q; }
    __syncthreads();
    s = ps[0] + ps[1] + ps[2] + ps[3];
    q = pq[0] + pq[1] + pq[2] + pq[3];
    float mu = s * (1.0f / DD);
    float var = q * (1.0f / DD) - mu * mu;
    float rstd = rsqrtf(var + 1e-5f);
    float4 gv = reinterpret_cast<const float4*>(g)[t];
    float4 bv = reinterpret_cast<const float4*>(b)[t];
    u16x4 o;
    o.x = f2bf((v.x - mu) * rstd * gv.x + bv.x);
    o.y = f2bf((v.y - mu) * rstd * gv.y + bv.y);
    o.z = f2bf((v.z - mu) * rstd * gv.z + bv.z);
    o.w = f2bf((v.w - mu) * rstd * gv.w + bv.w);
    reinterpret_cast<u16x4*>(out + (size_t)row * DD)[t] = o;
}

// -------- fused split-K reduce + LN: X1 = x+P0+P1+bias; LNout = LN(X1) --------
__global__ __launch_bounds__(256)
void k_redln(const float* __restrict__ x, const u16* __restrict__ P0,
             const u16* __restrict__ P1, const float* __restrict__ bias,
             const float* __restrict__ g, const float* __restrict__ be,
             float* __restrict__ X1, u16* __restrict__ LNout) {
    int row = blockIdx.x, t = threadIdx.x;
    size_t i = (size_t)row * 256 + t;
    float4 xv = reinterpret_cast<const float4*>(x)[i];
    u16x4 a = reinterpret_cast<const u16x4*>(P0)[i];
    u16x4 bb = reinterpret_cast<const u16x4*>(P1)[i];
    float4 bv = reinterpret_cast<const float4*>(bias)[t];
    float4 v;
    v.x = xv.x + bdec(a.x) + bdec(bb.x) + bv.x;
    v.y = xv.y + bdec(a.y) + bdec(bb.y) + bv.y;
    v.z = xv.z + bdec(a.z) + bdec(bb.z) + bv.z;
    v.w = xv.w + bdec(a.w) + bdec(bb.w) + bv.w;
    reinterpret_cast<float4*>(X1)[i] = v;
    float s = v.x + v.y + v.z + v.w;
    float q = v.x * v.x + v.y * v.y + v.z * v.z + v.w * v.w;
    #pragma unroll
    for (int m = 1; m < 64; m <<= 1) { s += __shfl_xor(s, m); q += __shfl_xor(q, m); }
    __shared__ float ps[4], pq[4];
    int w = t >> 6, l = t & 63;
    if (l == 0) { ps[w] = s; pq[w] = q; }
    __syncthreads();
    s = ps[0] + ps[1] + ps[2] + ps[3];
    q = pq[0] + pq[1] + pq[2] + pq[3];
    float mu = s * (1.0f / DD);
    float var = q * (1.0f / DD) - mu * mu;
    float rstd = rsqrtf(var + 1e-5f);
    float4 gv = reinterpret_cast<const float4*>(g)[t];
    float4 ev = reinterpret_cast<const float4*>(be)[t];
    u16x4 o;
    o.x = f2bf((v.x - mu) * rstd * gv.x + ev.x);
    o.y = f2bf((v.y - mu) * rstd * gv.y + ev.y);
    o.z = f2bf((v.z - mu) * rstd * gv.z + ev.z);
    o.w = f2bf((v.w - mu) * rstd * gv.w + ev.w);
    reinterpret_cast<u16x4*>(LNout + (size_t)row * DD)[t] = o;
}

// --------- qkv GEMM: 128x128, 2-phase counted-vmcnt, XCD-swizzled grid --------
__global__ __launch_bounds__(256)
void k_gemm_qkv(const u16* __restrict__ A, const u16* __restrict__ BT,
                u16* __restrict__ Cb, int M, int N, int K) {
    __shared__ __align__(128) char lds[2][32768];
    const int t = threadIdx.x;
    const int w = t >> 6, l = t & 63;
    const int lg = l >> 4, lr = l & 15;
    // XCD swizzle: consecutive logical n-blocks (same A-panel) share an XCD
    const int GX = gridDim.x;
    const int T = GX * gridDim.y;
    const int H = blockIdx.x + blockIdx.y * GX;
    const int L = (H & 7) * (T >> 3) + (H >> 3);
    const int m0 = (L / GX) * 128, n0 = (L % GX) * 128;
    const int wr = w >> 1, wc = w & 1;

    const int csw = ((l & 7) ^ (l >> 3)) << 3;
    const int chunk0 = w * 4;
    const int srow = (l >> 3);

    f32x4 acc[4][4];
    #pragma unroll
    for (int i = 0; i < 4; i++)
        #pragma unroll
        for (int j = 0; j < 4; j++)
            acc[i][j] = (f32x4){0.f, 0.f, 0.f, 0.f};

    #pragma unroll
    for (int i = 0; i < 4; i++) {
        const int chunk = chunk0 + i;
        const int r = chunk * 8 + srow;
        __builtin_amdgcn_global_load_lds(GLD_AS1(A  + (size_t)(m0 + r) * K + csw),
                                         GLD_AS3(lds[0] + chunk * 1024), 16, 0, 0);
        __builtin_amdgcn_global_load_lds(GLD_AS1(BT + (size_t)(n0 + r) * K + csw),
                                         GLD_AS3(lds[0] + 16384 + chunk * 1024), 16, 0, 0);
    }

    int buf = 0;
    for (int kt = 0; kt < K; kt += 64) {
        if (kt + 64 < K) {
            #pragma unroll
            for (int i = 0; i < 4; i++) {
                const int chunk = chunk0 + i;
                const int r = chunk * 8 + srow;
                __builtin_amdgcn_global_load_lds(GLD_AS1(A  + (size_t)(m0 + r) * K + kt + 64 + csw),
                                                 GLD_AS3(lds[buf ^ 1] + chunk * 1024), 16, 0, 0);
                __builtin_amdgcn_global_load_lds(GLD_AS1(BT + (size_t)(n0 + r) * K + kt + 64 + csw),
                                                 GLD_AS3(lds[buf ^ 1] + 16384 + chunk * 1024), 16, 0, 0);
            }
            WAIT_BAR(8);
        } else {
            WAIT_BAR(0);
        }
        const char* Al = lds[buf];
        const char* Bl = lds[buf] + 16384;
        #pragma unroll
        for (int s = 0; s < 2; s++) {
            const int swz = (s * 64 + lg * 16) ^ ((lr & 7) << 4);
            bf16x8 af[4], bfr[4];
            #pragma unroll
            for (int mi = 0; mi < 4; mi++)
                af[mi] = *reinterpret_cast<const bf16x8*>(Al + (wr * 64 + mi * 16 + lr) * 128 + swz);
            #pragma unroll
            for (int ni = 0; ni < 4; ni++)
                bfr[ni] = *reinterpret_cast<const bf16x8*>(Bl + (wc * 64 + ni * 16 + lr) * 128 + swz);
            #pragma unroll
            for (int mi = 0; mi < 4; mi++)
                #pragma unroll
                for (int ni = 0; ni < 4; ni++)
                    acc[mi][ni] = MFMA(af[mi], bfr[ni], acc[mi][ni]);
        }
        BAR();
        buf ^= 1;
    }

    #pragma unroll
    for (int mi = 0; mi < 4; mi++) {
        #pragma unroll
        for (int ni = 0; ni < 4; ni++) {
            int nn = n0 + wc * 64 + ni * 16 + lr;
            #pragma unroll
            for (int r = 0; r < 4; r++) {
                int mm = m0 + wr * 64 + mi * 16 + lg * 4 + r;
                float v = acc[mi][ni][r];
                float sv = (nn < 1024) ? v * 0.18033688011112042f : v;
                Cb[(size_t)mm * NQKV + nn] = f2bf(sv);
            }
        }
    }
}

// ---- ff1 GEMM: 256x256, fine-grained 4-phase/tile, counted vmcnt, setprio ----
// XCD-swizzled grid.
__global__ __launch_bounds__(512, 2)
void k_gemm_ff1(const u16* __restrict__ A, const u16* __restrict__ BT,
                u16* __restrict__ Cb, const float* __restrict__ bias,
                int M, int N, int K) {
    __shared__ __align__(128) char lds[2][65536];   // per buf: A h0,h1 | B h0,h1 (16KB each)
    const int t = threadIdx.x;
    const int w = t >> 6, l = t & 63;
    const int lg = l >> 4, lr = l & 15;
    const int GX = gridDim.x;
    const int T = GX * gridDim.y;
    const int H = blockIdx.x + blockIdx.y * GX;
    const int L = (H & 7) * (T >> 3) + (H >> 3);
    const int m0 = (L / GX) * 256, n0 = (L % GX) * 256;
    const int wr = w >> 2, wc = w & 3;

    const int csw = ((l & 7) ^ (l >> 3)) << 3;   // pre-swizzled source col (elems)
    const int srow8 = l >> 3;
    const int swzc = (lr & 7) << 4;              // read-side byte xor

    f32x4 acc[8][4];
    #pragma unroll
    for (int i = 0; i < 8; i++)
        #pragma unroll
        for (int j = 0; j < 4; j++)
            acc[i][j] = (f32x4){0.f, 0.f, 0.f, 0.f};

    auto STAGEH = [&](int bf, int which, int half, int kt) {
        const u16* sb = which ? BT : A;
        const int rb = which ? n0 : m0;
        char* dst = lds[bf] + which * 32768 + half * 16384 + w * 1024;
        #pragma unroll
        for (int j = 0; j < 2; j++) {
            const int r = half * 128 + (j * 8 + w) * 8 + srow8;
            __builtin_amdgcn_global_load_lds(GLD_AS1(sb + (size_t)(rb + r) * K + kt + csw),
                                             GLD_AS3(dst + j * 8192), 16, 0, 0);
        }
    };

    // prologue: tile 0's 4 halves into buf 0 (8 loads/thread)
    STAGEH(0, 0, 0, 0); STAGEH(0, 0, 1, 0); STAGEH(0, 1, 0, 0); STAGEH(0, 1, 1, 0);

    const int nt = K >> 6;
    int buf = 0;
    for (int tt = 0; tt < nt; ++tt) {
        const int nb = buf ^ 1;
        const bool pre = (tt + 1 < nt);
        const char* Abase = lds[buf];
        const char* Bbase = lds[buf] + 32768;

        bf16x8 Bf[4][2];
        #pragma unroll
        for (int p = 0; p < 4; p++) {
            if (pre) STAGEH(nb, p >> 1, p & 1, (tt + 1) * 64);
            if (p == 0) {
                if (pre) { WAIT_BAR(2); } else { WAIT_BAR(0); }
                #pragma unroll
                for (int ni = 0; ni < 4; ni++)
                    #pragma unroll
                    for (int ks = 0; ks < 2; ks++)
                        Bf[ni][ks] = *reinterpret_cast<const bf16x8*>(
                            Bbase + (wc >> 1) * 16384 + ((wc & 1) * 64 + ni * 16 + lr) * 128
                                  + ((ks * 64 + lg * 16) ^ swzc));
            }
            bf16x8 Af[2][2];
            #pragma unroll
            for (int mi2 = 0; mi2 < 2; mi2++)
                #pragma unroll
                for (int ks = 0; ks < 2; ks++)
                    Af[mi2][ks] = *reinterpret_cast<const bf16x8*>(
                        Abase + wr * 16384 + ((p * 2 + mi2) * 16 + lr) * 128
                              + ((ks * 64 + lg * 16) ^ swzc));
            __builtin_amdgcn_s_setprio(1);
            #pragma unroll
            for (int mi2 = 0; mi2 < 2; mi2++)
                #pragma unroll
                for (int ni = 0; ni < 4; ni++)
                    #pragma unroll
                    for (int ks = 0; ks < 2; ks++)
                        acc[p * 2 + mi2][ni] = MFMA(Af[mi2][ks], Bf[ni][ks], acc[p * 2 + mi2][ni]);
            __builtin_amdgcn_s_setprio(0);
            BAR();
        }
        buf = nb;
    }

    #pragma unroll
    for (int mi = 0; mi < 8; mi++) {
        #pragma unroll
        for (int ni = 0; ni < 4; ni++) {
            int nn = n0 + wc * 64 + ni * 16 + lr;
            #pragma unroll
            for (int r = 0; r < 4; r++) {
                int mm = m0 + wr * 128 + mi * 16 + lg * 4 + r;
                float u = acc[mi][ni][r] + bias[nn];
                float u3 = u * u * u;
                float gl = u / (1.0f + exp2f(-2.3022077f * u - 0.10294276f * u3));
                Cb[(size_t)mm * N + nn] = f2bf(gl);
            }
        }
    }
}

// ----- 128x128 GEMM (split-K partials), 2-phase pipeline, XCD-swizzled -------
__global__ __launch_bounds__(256)
void k_gemm_sk(const u16* __restrict__ A, const u16* __restrict__ BT,
               u16* __restrict__ P0, u16* __restrict__ P1, int M, int N, int K) {
    __shared__ __align__(128) char lds[2][32768];
    const int t = threadIdx.x;
    const int w = t >> 6, l = t & 63;
    const int lg = l >> 4, lr = l & 15;
    const int GX = gridDim.x, GY = gridDim.y;
    const int T = GX * GY * gridDim.z;
    const int H = blockIdx.x + blockIdx.y * GX + blockIdx.z * GX * GY;
    const int L = (H & 7) * (T >> 3) + (H >> 3);
    const int n0 = (L % GX) * 128;
    const int m0 = ((L / GX) % GY) * 128;
    const int zz = L / (GX * GY);
    const int wr = w >> 1, wc = w & 1;

    const int kh = K >> 1;
    const int kbeg = zz * kh;
    const int kend = kbeg + kh;

    const int csw = ((l & 7) ^ (l >> 3)) << 3;
    const int chunk0 = w * 4;
    const int srow = (l >> 3);

    f32x4 acc[4][4];
    #pragma unroll
    for (int i = 0; i < 4; i++)
        #pragma unroll
        for (int j = 0; j < 4; j++)
            acc[i][j] = (f32x4){0.f, 0.f, 0.f, 0.f};

    #pragma unroll
    for (int i = 0; i < 4; i++) {
        const int chunk = chunk0 + i;
        const int r = chunk * 8 + srow;
        __builtin_amdgcn_global_load_lds(GLD_AS1(A  + (size_t)(m0 + r) * K + kbeg + csw),
                                         GLD_AS3(lds[0] + chunk * 1024), 16, 0, 0);
        __builtin_amdgcn_global_load_lds(GLD_AS1(BT + (size_t)(n0 + r) * K + kbeg + csw),
                                         GLD_AS3(lds[0] + 16384 + chunk * 1024), 16, 0, 0);
    }

    int buf = 0;
    for (int kt = kbeg; kt < kend; kt += 64) {
        if (kt + 64 < kend) {
            #pragma unroll
            for (int i = 0; i < 4; i++) {
                const int chunk = chunk0 + i;
                const int r = chunk * 8 + srow;
                __builtin_amdgcn_global_load_lds(GLD_AS1(A  + (size_t)(m0 + r) * K + kt + 64 + csw),
                                                 GLD_AS3(lds[buf ^ 1] + chunk * 1024), 16, 0, 0);
                __builtin_amdgcn_global_load_lds(GLD_AS1(BT + (size_t)(n0 + r) * K + kt + 64 + csw),
                                                 GLD_AS3(lds[buf ^ 1] + 16384 + chunk * 1024), 16, 0, 0);
            }
            WAIT_BAR(8);
        } else {
            WAIT_BAR(0);
        }
        const char* Al = lds[buf];
        const char* Bl = lds[buf] + 16384;
        #pragma unroll
        for (int s = 0; s < 2; s++) {
            const int swz = (s * 64 + lg * 16) ^ ((lr & 7) << 4);
            bf16x8 af[4], bfr[4];
            #pragma unroll
            for (int mi = 0; mi < 4; mi++)
                af[mi] = *reinterpret_cast<const bf16x8*>(Al + (wr * 64 + mi * 16 + lr) * 128 + swz);
            #pragma unroll
            for (int ni = 0; ni < 4; ni++)
                bfr[ni] = *reinterpret_cast<const bf16x8*>(Bl + (wc * 64 + ni * 16 + lr) * 128 + swz);
            #pragma unroll
            for (int mi = 0; mi < 4; mi++)
                #pragma unroll
                for (int ni = 0; ni < 4; ni++)
                    acc[mi][ni] = MFMA(af[mi], bfr[ni], acc[mi][ni]);
        }
        BAR();
        buf ^= 1;
    }

    u16* dst = zz ? P1 : P0;
    #pragma unroll
    for (int mi = 0; mi < 4; mi++) {
        #pragma unroll
        for (int ni = 0; ni < 4; ni++) {
            int nn = n0 + wc * 64 + ni * 16 + lr;
            #pragma unroll
            for (int r = 0; r < 4; r++) {
                int mm = m0 + wr * 64 + mi * 16 + lg * 4 + r;
                dst[(size_t)mm * N + nn] = f2bf(acc[mi][ni][r]);
            }
        }
    }
}

// ------------- final split-K reduce: OUT = RES + P0 + P1 + bias ---------------
__global__ __launch_bounds__(256)
void k_ffreduce(const float* __restrict__ RES, const u16* __restrict__ P0,
                const u16* __restrict__ P1, const float* __restrict__ bias,
                float* __restrict__ OUT) {
    int i = blockIdx.x * 256 + threadIdx.x;      // float4 index
    float4 xv = reinterpret_cast<const float4*>(RES)[i];
    u16x4 a = reinterpret_cast<const u16x4*>(P0)[i];
    u16x4 b = reinterpret_cast<const u16x4*>(P1)[i];
    float4 bv = reinterpret_cast<const float4*>(bias)[i & (DD / 4 - 1)];
    float4 o;
    o.x = xv.x + bdec(a.x) + bdec(b.x) + bv.x;
    o.y = xv.y + bdec(a.y) + bdec(b.y) + bv.y;
    o.z = xv.z + bdec(a.z) + bdec(b.z) + bv.z;
    o.w = xv.w + bdec(a.w) + bdec(b.w) + bv.w;
    reinterpret_cast<float4*>(OUT)[i] = o;
}

// ------- flash attention, swapped-QK 32x32, KVBLK=64, cross-iter pipeline ------
// + s_setprio around MFMA clusters (T5).
__global__ __launch_bounds__(256)
void k_attn(const u16* __restrict__ qkv, const u16* __restrict__ vT,
            u16* __restrict__ out) {
    const int w = threadIdx.x >> 6, l = threadIdx.x & 63;
    const int q = l & 31, hi = l >> 5;
    const int task = (blockIdx.x & 7) * 64 + (blockIdx.x >> 3);  // 512-block bijection
    const int bh = task >> 4;                // 0..31 (4 heads per XCD)
    const int qg = task & 15;
    const int b = bh >> 4, h = bh & 15;
    const size_t rowbase = (size_t)b * SS;
    const int q0 = (qg * 4 + w) * 32;

    __shared__ __align__(128) u16 Kl[3][64 * 64];   // triple buffer (stage depth 2)
    __shared__ __align__(128) u16 Vl[2][64 * 64];   // double buffer

    const u16* kbase = qkv + rowbase * NQKV + 1024 + h * DH;
    const u16* vbase = vT + (size_t)bh * DH * SS;

    const int srow8 = l >> 3;
    const int sslot = (l & 7) ^ srow8;
    const int kr0 = w * 8 + srow8;
    const u16* kg0 = kbase + (size_t)kr0 * NQKV + sslot * 8;
    const u16* kg1 = kbase + (size_t)(kr0 + 32) * NQKV + sslot * 8;
    const u16* vg0 = vbase + (size_t)kr0 * SS + sslot * 8;
    const u16* vg1 = vbase + (size_t)(kr0 + 32) * SS + sslot * 8;
    const int chA = (w * 8) * 64, chB = (w * 8 + 32) * 64;

    const u16* qrow = qkv + (rowbase + q0 + q) * NQKV + h * DH + hi * 8;
    bf16x8 qf[4];
    #pragma unroll
    for (int ks = 0; ks < 4; ks++)
        qf[ks] = *reinterpret_cast<const bf16x8*>(qrow + ks * 16);
    asm volatile("s_waitcnt vmcnt(0)" ::: "memory");

    bf16x8 onesf;
    #pragma unroll
    for (int i = 0; i < 8; i++) onesf[i] = (__bf16)1.0f;

    f32x16 o0 = zero16(), o1 = zero16();
    f32x16 lacc = zero16();
    const int qsw = (q & 7) << 3;

    __builtin_amdgcn_global_load_lds(GLD_AS1(kg0), GLD_AS3((u16*)Kl[0] + chA), 16, 0, 0);
    __builtin_amdgcn_global_load_lds(GLD_AS1(kg1), GLD_AS3((u16*)Kl[0] + chB), 16, 0, 0);
    __builtin_amdgcn_global_load_lds(GLD_AS1(kg0 + (size_t)64 * NQKV), GLD_AS3((u16*)Kl[1] + chA), 16, 0, 0);
    __builtin_amdgcn_global_load_lds(GLD_AS1(kg1 + (size_t)64 * NQKV), GLD_AS3((u16*)Kl[1] + chB), 16, 0, 0);
    __builtin_amdgcn_global_load_lds(GLD_AS1(vg0), GLD_AS3((u16*)Vl[0] + chA), 16, 0, 0);
    __builtin_amdgcn_global_load_lds(GLD_AS1(vg1), GLD_AS3((u16*)Vl[0] + chB), 16, 0, 0);
    WAIT_BAR(4);

    f32x16 scA0 = zero16(), scA1 = zero16();
    {
        const u16* Kb = Kl[0];
        #pragma unroll
        for (int ks = 0; ks < 4; ks++) {
            const int off = (ks * 16 + hi * 8) ^ qsw;
            bf16x8 kf0 = *reinterpret_cast<const bf16x8*>(Kb + q * 64 + off);
            bf16x8 kf1 = *reinterpret_cast<const bf16x8*>(Kb + (q + 32) * 64 + off);
            scA0 = MFMA32(kf0, qf[ks], scA0);
            scA1 = MFMA32(kf1, qf[ks], scA1);
        }
    }

    int kRead = 1, vRead = 0;
    for (int i = 0; i < 32; ++i) {
        const int kStage = (kRead == 2) ? 0 : kRead + 1;
        if (i + 2 < 32) {
            const size_t koff = (size_t)(i + 2) * 64 * NQKV;
            __builtin_amdgcn_global_load_lds(GLD_AS1(kg0 + koff), GLD_AS3((u16*)Kl[kStage] + chA), 16, 0, 0);
            __builtin_amdgcn_global_load_lds(GLD_AS1(kg1 + koff), GLD_AS3((u16*)Kl[kStage] + chB), 16, 0, 0);
            WAIT_BAR(2);
        } else {
            WAIT_BAR(0);
        }
        if (i + 1 < 32) {
            const int voff = (i + 1) * 64;
            __builtin_amdgcn_global_load_lds(GLD_AS1(vg0 + voff), GLD_AS3((u16*)Vl[vRead ^ 1] + chA), 16, 0, 0);
            __builtin_amdgcn_global_load_lds(GLD_AS1(vg1 + voff), GLD_AS3((u16*)Vl[vRead ^ 1] + chB), 16, 0, 0);
        }

        f32x16 p0, p1;
        #pragma unroll
        for (int j = 0; j < 16; j++) p0[j] = exp2f(scA0[j]);
        #pragma unroll
        for (int j = 0; j < 16; j++) p1[j] = exp2f(scA1[j]);

        f32x16 stB0 = zero16(), stB1 = zero16();
        if (i + 1 < 32) {
            const u16* Kb = Kl[kRead];
            __builtin_amdgcn_s_setprio(1);
            #pragma unroll
            for (int ks = 0; ks < 4; ks++) {
                const int off = (ks * 16 + hi * 8) ^ qsw;
                bf16x8 kf0 = *reinterpret_cast<const bf16x8*>(Kb + q * 64 + off);
                bf16x8 kf1 = *reinterpret_cast<const bf16x8*>(Kb + (q + 32) * 64 + off);
                stB0 = MFMA32(kf0, qf[ks], stB0);
                stB1 = MFMA32(kf1, qf[ks], stB1);
            }
            __builtin_amdgcn_s_setprio(0);
        }

        union W { unsigned int u; __bf16 h[2]; };
        W pw[16];
        #pragma unroll
        for (int m = 0; m < 8; m++) {
            pw[m].h[0] = (__bf16)p0[2 * m];
            pw[m].h[1] = (__bf16)p0[2 * m + 1];
            pw[8 + m].h[0] = (__bf16)p1[2 * m];
            pw[8 + m].h[1] = (__bf16)p1[2 * m + 1];
        }
        bf16x8 pf[4];
        #pragma unroll
        for (int kk = 0; kk < 4; kk++) {
            const int base = (kk >> 1) * 8 + (kk & 1) * 4;
            unsigned int a0 = pw[base + 0].u, a1 = pw[base + 1].u;
            unsigned int b0 = pw[base + 2].u, b1 = pw[base + 3].u;
            unsigned int own0 = hi ? b0 : a0, own1 = hi ? b1 : a1;
            unsigned int snd0 = hi ? a0 : b0, snd1 = hi ? a1 : b1;
            unsigned int r0 = __shfl_xor(snd0, 32), r1 = __shfl_xor(snd1, 32);
            union F { unsigned int u[4]; bf16x8 v; } f;
            f.u[0] = hi ? r0 : own0;
            f.u[1] = hi ? r1 : own1;
            f.u[2] = hi ? own0 : r0;
            f.u[3] = hi ? own1 : r1;
            pf[kk] = f.v;
        }

        const u16* Vb = Vl[vRead];
        __builtin_amdgcn_s_setprio(1);
        #pragma unroll
        for (int kk = 0; kk < 4; kk++) {
            const int off = (kk * 16 + hi * 8) ^ qsw;
            bf16x8 v0 = *reinterpret_cast<const bf16x8*>(Vb + q * 64 + off);
            bf16x8 v1 = *reinterpret_cast<const bf16x8*>(Vb + (q + 32) * 64 + off);
            lacc = MFMA32(onesf, pf[kk], lacc);
            o0 = MFMA32(v0, pf[kk], o0);
            o1 = MFMA32(v1, pf[kk], o1);
        }
        __builtin_amdgcn_s_setprio(0);

        scA0 = stB0;
        scA1 = stB1;
        kRead = kStage;
        vRead ^= 1;
    }

    float invl = 1.0f / lacc[0];
    u16* orow = out + (rowbase + q0 + q) * DD + h * DH + hi * 4;
    #pragma unroll
    for (int a = 0; a < 4; a++) {
        u16x4 s0v, s1v;
        #pragma unroll
        for (int i = 0; i < 4; i++) {
            s0v[i] = f2bf(o0[4 * a + i] * invl);
            s1v[i] = f2bf(o1[4 * a + i] * invl);
        }
        *reinterpret_cast<u16x4*>(orow + 8 * a)      = s0v;
        *reinterpret_cast<u16x4*>(orow + 32 + 8 * a) = s1v;
    }
}

extern "C" void kernel_launch(void* const* d_in, const int* in_sizes, int n_in,
                              void* d_out, int out_size, void* d_ws, size_t ws_size,
                              hipStream_t stream) {
    (void)in_sizes; (void)n_in; (void)out_size; (void)ws_size;
    const float* x     = (const float*)d_in[0];
    const float* w_qkv = (const float*)d_in[1];
    const float* w_out = (const float*)d_in[2];
    const float* b_out = (const float*)d_in[3];
    const float* g1    = (const float*)d_in[4];
    const float* be1   = (const float*)d_in[5];
    const float* g2    = (const float*)d_in[6];
    const float* be2   = (const float*)d_in[7];
    const float* w_ff1 = (const float*)d_in[8];
    const float* b_ff1 = (const float*)d_in[9];
    const float* w_ff2 = (const float*)d_in[10];
    const float* b_ff2 = (const float*)d_in[11];

    char* ws = (char*)d_ws;
    u16*   W  = (u16*)(ws);                  //  8.39 MB  (weight^T scratch, reused)
    u16*   Hb = (u16*)(ws + 8388608);        //  8.39 MB  (LN1 out; later partials)
    u16*   QF = (u16*)(ws + 16777216);       // 33.55 MB  (qkv, later ffn act)
    u16*   VT = (u16*)(ws + 50331648);       //  8.39 MB  (v^T; later partials)
    u16*   AO = (u16*)(ws + 58720256);       //  8.39 MB  (attn out; later LN2 out)
    float* X1 = (float*)(ws + 67108864);     // 16.78 MB  (post-attn residual fp32)
    float* OUT = (float*)d_out;

    // LN1: x -> Hb
    k_layernorm<<<NTOK, 256, 0, stream>>>(x, g1, be1, Hb);
    // w_qkv^T
    k_transpose<<<dim3(3072 / 32, 1024 / 32), dim3(32, 8), 0, stream>>>(w_qkv, W, 1024, 3072);
    // qkv = Hb @ w_qkv  (128^2 2-phase, XCD-swizzled; q cols pre-scaled)
    k_gemm_qkv<<<dim3(3072 / 128, 4096 / 128), 256, 0, stream>>>(
        Hb, W, QF, NTOK, NQKV, 1024);
    // V transpose (coalesced both sides)
    k_transpose_v<<<4096, 256, 0, stream>>>(QF, VT);
    // attention (512 blocks, XCD-swizzled, KVBLK=64, cross-iter pipelined, setprio)
    k_attn<<<512, 256, 0, stream>>>(QF, VT, AO);
    // w_out^T
    k_transpose<<<dim3(1024 / 32, 1024 / 32), dim3(32, 8), 0, stream>>>(w_out, W, 1024, 1024);
    // attn-out split-K x2: partials P0 -> Hb, P1 -> VT
    k_gemm_sk<<<dim3(1024 / 128, 4096 / 128, 2), 256, 0, stream>>>(
        AO, W, Hb, VT, NTOK, 1024, 1024);
    // fused: X1 = x + P0 + P1 + b_out ; AO = LN2(X1)
    k_redln<<<NTOK, 256, 0, stream>>>(x, Hb, VT, b_out, g2, be2, X1, AO);
    // w_ff1^T
    k_transpose<<<dim3(4096 / 32, 1024 / 32), dim3(32, 8), 0, stream>>>(w_ff1, W, 1024, 4096);
    // FFA = gelu(AO @ w_ff1 + b_ff1) -> QF   (256^2 fine-grained, XCD-swizzled)
    k_gemm_ff1<<<dim3(4096 / 256, 4096 / 256), 512, 0, stream>>>(
        AO, W, QF, b_ff1, NTOK, 4096, 1024);
    // w_ff2^T
    k_transpose<<<dim3(1024 / 32, 4096 / 32), dim3(32, 8), 0, stream>>>(w_ff2, W, 4096, 1024);
    // ff2 split-K x2: partials P0 -> VT, P1 -> Hb
    k_gemm_sk<<<dim3(1024 / 128, 4096 / 128, 2), 256, 0, stream>>>(
        QF, W, VT, Hb, NTOK, 1024, 4096);
    // OUT = X1 + P0 + P1 + b_ff2
    k_ffreduce<<<NTOK * DD / 4 / 256, 256, 0, stream>>>(X1, VT, Hb, b_ff2, OUT);
}

// Round 15
// 249.944 us; speedup vs baseline: 1.0492x; 1.0092x over previous
//
#include <hip/hip_runtime.h>
#include <math.h>

typedef unsigned short u16;
typedef __attribute__((ext_vector_type(4))) float f32x4;
typedef __attribute__((ext_vector_type(16))) float f32x16;
typedef __attribute__((ext_vector_type(4))) unsigned short u16x4;
typedef __attribute__((ext_vector_type(8))) __bf16 bf16x8;

static constexpr int SS   = 2048;   // seq len
static constexpr int DD   = 1024;   // model dim
static constexpr int HH   = 16;     // heads
static constexpr int DH   = 64;     // head dim
static constexpr int NTOK = 4096;   // B*S
static constexpr int NQKV = 3072;

#define DEV static __device__ __forceinline__
#define GLD_AS1(p) ((__attribute__((address_space(1))) void*)(void*)(p))
#define GLD_AS3(p) ((__attribute__((address_space(3))) void*)(p))

// fused counted-wait + barrier (T4)
#define WAIT_BAR(N) asm volatile("s_waitcnt vmcnt(" #N ")\n\ts_barrier" ::: "memory")
#define BAR()       asm volatile("s_barrier" ::: "memory")

DEV u16 f2bf(float f) {
    union { float f; unsigned int i; } v; v.f = f;
    unsigned int r = v.i + 0x7fffu + ((v.i >> 16) & 1u);
    return (u16)(r >> 16);
}
DEV float bdec(u16 u) {
    union { unsigned int i; float f; } v; v.i = ((unsigned int)u) << 16; return v.f;
}

DEV f32x4 MFMA(bf16x8 a, bf16x8 b, f32x4 c) {
    return __builtin_amdgcn_mfma_f32_16x16x32_bf16(a, b, c, 0, 0, 0);
}
DEV f32x16 MFMA32(bf16x8 a, bf16x8 b, f32x16 c) {
    return __builtin_amdgcn_mfma_f32_32x32x16_bf16(a, b, c, 0, 0, 0);
}
DEV f32x16 zero16() {
    f32x16 z;
    #pragma unroll
    for (int i = 0; i < 16; i++) z[i] = 0.f;
    return z;
}

// ---------------- transpose fp32 [R][C] -> bf16 [C][R] ----------------
__global__ __launch_bounds__(256)
void k_transpose(const float* __restrict__ in, u16* __restrict__ out, int R, int C) {
    __shared__ float tile[32][33];
    int c0 = blockIdx.x * 32, r0 = blockIdx.y * 32;
    int tx = threadIdx.x, ty = threadIdx.y; // 32 x 8
    #pragma unroll
    for (int i = 0; i < 32; i += 8)
        tile[ty + i][tx] = in[(size_t)(r0 + ty + i) * C + c0 + tx];
    __syncthreads();
    #pragma unroll
    for (int i = 0; i < 32; i += 8)
        out[(size_t)(c0 + ty + i) * R + r0 + tx] = f2bf(tile[tx][ty + i]);
}

// ------------- bf16 V transpose: qkv v-cols [s][d] -> vT[bh][d][s] -------------
__global__ __launch_bounds__(256)
void k_transpose_v(const u16* __restrict__ qkv, u16* __restrict__ vT) {
    __shared__ u16 tile[32][33];
    int bid = blockIdx.x;
    int st = bid & 63;           // s tile (2048/32)
    int dt = (bid >> 6) & 1;     // d tile (64/32)
    int bh = bid >> 7;           // 0..31
    int b = bh >> 4, h = bh & 15;
    int s0 = st * 32, d0 = dt * 32;
    int tx = threadIdx.x & 31, ty = threadIdx.x >> 5;   // 32 x 8
    const u16* src = qkv + ((size_t)(b * SS + s0)) * NQKV + 2048 + h * DH + d0;
    #pragma unroll
    for (int i = 0; i < 32; i += 8)
        tile[ty + i][tx] = src[(size_t)(ty + i) * NQKV + tx];
    __syncthreads();
    u16* dst = vT + ((size_t)bh * DH + d0) * SS + s0;
    #pragma unroll
    for (int i = 0; i < 32; i += 8)
        dst[(size_t)(ty + i) * SS + tx] = tile[tx][ty + i];
}

// ---------------- layernorm fp32 -> bf16, one block per row ----------------
__global__ __launch_bounds__(256)
void k_layernorm(const float* __restrict__ x, const float* __restrict__ g,
                 const float* __restrict__ b, u16* __restrict__ out) {
    int row = blockIdx.x, t = threadIdx.x;
    const float4* xp = reinterpret_cast<const float4*>(x + (size_t)row * DD);
    float4 v = xp[t];
    float s = v.x + v.y + v.z + v.w;
    float q = v.x * v.x + v.y * v.y + v.z * v.z + v.w * v.w;
    #pragma unroll
    for (int m = 1; m < 64; m <<= 1) { s += __shfl_xor(s, m); q += __shfl_xor(q, m); }
    __shared__ float ps[4], pq[4];
    int w = t >> 6, l = t & 63;
    if (l == 0) { ps[w] = s; pq[w] = q; }
    __syncthreads();
    s = ps[0] + ps[1] + ps[2] + ps[3];
    q = pq[0] + pq[1] + pq[2] + pq[3];
    float mu = s * (1.0f / DD);
    float var = q * (1.0f / DD) - mu * mu;
    float rstd = rsqrtf(var + 1e-5f);
    float4 gv = reinterpret_cast<const float4*>(g)[t];
    float4 bv = reinterpret_cast<const float4*>(b)[t];
    u16x4 o;
    o.x = f2bf((v.x - mu) * rstd * gv.x + bv.x);
    o.y = f2bf((v.y - mu) * rstd * gv.y + bv.y);
    o.z = f2bf((v.z - mu) * rstd * gv.z + bv.z);
    o.w = f2bf((v.w - mu) * rstd * gv.w + bv.w);
    reinterpret_cast<u16x4*>(out + (size_t)row * DD)[t] = o;
}

// -------- fused split-K reduce + LN: X1 = x+P0+P1+bias; LNout = LN(X1) --------
__global__ __launch_bounds__(256)
void k_redln(const float* __restrict__ x, const u16* __restrict__ P0,
             const u16* __restrict__ P1, const float* __restrict__ bias,
             const float* __restrict__ g, const float* __restrict__ be,
             float* __restrict__ X1, u16* __restrict__ LNout) {
    int row = blockIdx.x, t = threadIdx.x;
    size_t i = (size_t)row * 256 + t;
    float4 xv = reinterpret_cast<const float4*>(x)[i];
    u16x4 a = reinterpret_cast<const u16x4*>(P0)[i];
    u16x4 bb = reinterpret_cast<const u16x4*>(P1)[i];
    float4 bv = reinterpret_cast<const float4*>(bias)[t];
    float4 v;
    v.x = xv.x + bdec(a.x) + bdec(bb.x) + bv.x;
    v.y = xv.y + bdec(a.y) + bdec(bb.y) + bv.y;
    v.z = xv.z + bdec(a.z) + bdec(bb.z) + bv.z;
    v.w = xv.w + bdec(a.w) + bdec(bb.w) + bv.w;
    reinterpret_cast<float4*>(X1)[i] = v;
    float s = v.x + v.y + v.z + v.w;
    float q = v.x * v.x + v.y * v.y + v.z * v.z + v.w * v.w;
    #pragma unroll
    for (int m = 1; m < 64; m <<= 1) { s += __shfl_xor(s, m); q += __shfl_xor(q, m); }
    __shared__ float ps[4], pq[4];
    int w = t >> 6, l = t & 63;
    if (l == 0) { ps[w] = s; pq[w] = q; }
    __syncthreads();
    s = ps[0] + ps[1] + ps[2] + ps[3];
    q = pq[0] + pq[1] + pq[2] + pq[3];
    float mu = s * (1.0f / DD);
    float var = q * (1.0f / DD) - mu * mu;
    float rstd = rsqrtf(var + 1e-5f);
    float4 gv = reinterpret_cast<const float4*>(g)[t];
    float4 ev = reinterpret_cast<const float4*>(be)[t];
    u16x4 o;
    o.x = f2bf((v.x - mu) * rstd * gv.x + ev.x);
    o.y = f2bf((v.y - mu) * rstd * gv.y + ev.y);
    o.z = f2bf((v.z - mu) * rstd * gv.z + ev.z);
    o.w = f2bf((v.w - mu) * rstd * gv.w + ev.w);
    reinterpret_cast<u16x4*>(LNout + (size_t)row * DD)[t] = o;
}

// --------- qkv GEMM: 128x128, 2-phase counted-vmcnt, XCD-swizzled grid --------
__global__ __launch_bounds__(256)
void k_gemm_qkv(const u16* __restrict__ A, const u16* __restrict__ BT,
                u16* __restrict__ Cb, int M, int N, int K) {
    __shared__ __align__(128) char lds[2][32768];
    const int t = threadIdx.x;
    const int w = t >> 6, l = t & 63;
    const int lg = l >> 4, lr = l & 15;
    const int GX = gridDim.x;
    const int T = GX * gridDim.y;
    const int H = blockIdx.x + blockIdx.y * GX;
    const int L = (H & 7) * (T >> 3) + (H >> 3);
    const int m0 = (L / GX) * 128, n0 = (L % GX) * 128;
    const int wr = w >> 1, wc = w & 1;

    const int csw = ((l & 7) ^ (l >> 3)) << 3;
    const int chunk0 = w * 4;
    const int srow = (l >> 3);

    f32x4 acc[4][4];
    #pragma unroll
    for (int i = 0; i < 4; i++)
        #pragma unroll
        for (int j = 0; j < 4; j++)
            acc[i][j] = (f32x4){0.f, 0.f, 0.f, 0.f};

    #pragma unroll
    for (int i = 0; i < 4; i++) {
        const int chunk = chunk0 + i;
        const int r = chunk * 8 + srow;
        __builtin_amdgcn_global_load_lds(GLD_AS1(A  + (size_t)(m0 + r) * K + csw),
                                         GLD_AS3(lds[0] + chunk * 1024), 16, 0, 0);
        __builtin_amdgcn_global_load_lds(GLD_AS1(BT + (size_t)(n0 + r) * K + csw),
                                         GLD_AS3(lds[0] + 16384 + chunk * 1024), 16, 0, 0);
    }

    int buf = 0;
    for (int kt = 0; kt < K; kt += 64) {
        if (kt + 64 < K) {
            #pragma unroll
            for (int i = 0; i < 4; i++) {
                const int chunk = chunk0 + i;
                const int r = chunk * 8 + srow;
                __builtin_amdgcn_global_load_lds(GLD_AS1(A  + (size_t)(m0 + r) * K + kt + 64 + csw),
                                                 GLD_AS3(lds[buf ^ 1] + chunk * 1024), 16, 0, 0);
                __builtin_amdgcn_global_load_lds(GLD_AS1(BT + (size_t)(n0 + r) * K + kt + 64 + csw),
                                                 GLD_AS3(lds[buf ^ 1] + 16384 + chunk * 1024), 16, 0, 0);
            }
            WAIT_BAR(8);
        } else {
            WAIT_BAR(0);
        }
        const char* Al = lds[buf];
        const char* Bl = lds[buf] + 16384;
        #pragma unroll
        for (int s = 0; s < 2; s++) {
            const int swz = (s * 64 + lg * 16) ^ ((lr & 7) << 4);
            bf16x8 af[4], bfr[4];
            #pragma unroll
            for (int mi = 0; mi < 4; mi++)
                af[mi] = *reinterpret_cast<const bf16x8*>(Al + (wr * 64 + mi * 16 + lr) * 128 + swz);
            #pragma unroll
            for (int ni = 0; ni < 4; ni++)
                bfr[ni] = *reinterpret_cast<const bf16x8*>(Bl + (wc * 64 + ni * 16 + lr) * 128 + swz);
            #pragma unroll
            for (int mi = 0; mi < 4; mi++)
                #pragma unroll
                for (int ni = 0; ni < 4; ni++)
                    acc[mi][ni] = MFMA(af[mi], bfr[ni], acc[mi][ni]);
        }
        BAR();
        buf ^= 1;
    }

    #pragma unroll
    for (int mi = 0; mi < 4; mi++) {
        #pragma unroll
        for (int ni = 0; ni < 4; ni++) {
            int nn = n0 + wc * 64 + ni * 16 + lr;
            #pragma unroll
            for (int r = 0; r < 4; r++) {
                int mm = m0 + wr * 64 + mi * 16 + lg * 4 + r;
                float v = acc[mi][ni][r];
                float sv = (nn < 1024) ? v * 0.18033688011112042f : v;
                Cb[(size_t)mm * NQKV + nn] = f2bf(sv);
            }
        }
    }
}

// ---- ff1 GEMM: 256x256, fine-grained 4-phase/tile, counted vmcnt, setprio ----
__global__ __launch_bounds__(512, 2)
void k_gemm_ff1(const u16* __restrict__ A, const u16* __restrict__ BT,
                u16* __restrict__ Cb, const float* __restrict__ bias,
                int M, int N, int K) {
    __shared__ __align__(128) char lds[2][65536];   // per buf: A h0,h1 | B h0,h1 (16KB each)
    const int t = threadIdx.x;
    const int w = t >> 6, l = t & 63;
    const int lg = l >> 4, lr = l & 15;
    const int GX = gridDim.x;
    const int T = GX * gridDim.y;
    const int H = blockIdx.x + blockIdx.y * GX;
    const int L = (H & 7) * (T >> 3) + (H >> 3);
    const int m0 = (L / GX) * 256, n0 = (L % GX) * 256;
    const int wr = w >> 2, wc = w & 3;

    const int csw = ((l & 7) ^ (l >> 3)) << 3;   // pre-swizzled source col (elems)
    const int srow8 = l >> 3;
    const int swzc = (lr & 7) << 4;              // read-side byte xor

    f32x4 acc[8][4];
    #pragma unroll
    for (int i = 0; i < 8; i++)
        #pragma unroll
        for (int j = 0; j < 4; j++)
            acc[i][j] = (f32x4){0.f, 0.f, 0.f, 0.f};

    auto STAGEH = [&](int bf, int which, int half, int kt) {
        const u16* sb = which ? BT : A;
        const int rb = which ? n0 : m0;
        char* dst = lds[bf] + which * 32768 + half * 16384 + w * 1024;
        #pragma unroll
        for (int j = 0; j < 2; j++) {
            const int r = half * 128 + (j * 8 + w) * 8 + srow8;
            __builtin_amdgcn_global_load_lds(GLD_AS1(sb + (size_t)(rb + r) * K + kt + csw),
                                             GLD_AS3(dst + j * 8192), 16, 0, 0);
        }
    };

    // prologue: tile 0's 4 halves into buf 0 (8 loads/thread)
    STAGEH(0, 0, 0, 0); STAGEH(0, 0, 1, 0); STAGEH(0, 1, 0, 0); STAGEH(0, 1, 1, 0);

    const int nt = K >> 6;
    int buf = 0;
    for (int tt = 0; tt < nt; ++tt) {
        const int nb = buf ^ 1;
        const bool pre = (tt + 1 < nt);
        const char* Abase = lds[buf];
        const char* Bbase = lds[buf] + 32768;

        bf16x8 Bf[4][2];
        #pragma unroll
        for (int p = 0; p < 4; p++) {
            if (pre) STAGEH(nb, p >> 1, p & 1, (tt + 1) * 64);
            if (p == 0) {
                if (pre) { WAIT_BAR(2); } else { WAIT_BAR(0); }
                #pragma unroll
                for (int ni = 0; ni < 4; ni++)
                    #pragma unroll
                    for (int ks = 0; ks < 2; ks++)
                        Bf[ni][ks] = *reinterpret_cast<const bf16x8*>(
                            Bbase + (wc >> 1) * 16384 + ((wc & 1) * 64 + ni * 16 + lr) * 128
                                  + ((ks * 64 + lg * 16) ^ swzc));
            }
            bf16x8 Af[2][2];
            #pragma unroll
            for (int mi2 = 0; mi2 < 2; mi2++)
                #pragma unroll
                for (int ks = 0; ks < 2; ks++)
                    Af[mi2][ks] = *reinterpret_cast<const bf16x8*>(
                        Abase + wr * 16384 + ((p * 2 + mi2) * 16 + lr) * 128
                              + ((ks * 64 + lg * 16) ^ swzc));
            __builtin_amdgcn_s_setprio(1);
            #pragma unroll
            for (int mi2 = 0; mi2 < 2; mi2++)
                #pragma unroll
                for (int ni = 0; ni < 4; ni++)
                    #pragma unroll
                    for (int ks = 0; ks < 2; ks++)
                        acc[p * 2 + mi2][ni] = MFMA(Af[mi2][ks], Bf[ni][ks], acc[p * 2 + mi2][ni]);
            __builtin_amdgcn_s_setprio(0);
            BAR();
        }
        buf = nb;
    }

    #pragma unroll
    for (int mi = 0; mi < 8; mi++) {
        #pragma unroll
        for (int ni = 0; ni < 4; ni++) {
            int nn = n0 + wc * 64 + ni * 16 + lr;
            #pragma unroll
            for (int r = 0; r < 4; r++) {
                int mm = m0 + wr * 128 + mi * 16 + lg * 4 + r;
                float u = acc[mi][ni][r] + bias[nn];
                float u3 = u * u * u;
                float gl = u / (1.0f + exp2f(-2.3022077f * u - 0.10294276f * u3));
                Cb[(size_t)mm * N + nn] = f2bf(gl);
            }
        }
    }
}

// ----- 128x128 GEMM (split-K partials), 2-phase pipeline, XCD-swizzled -------
__global__ __launch_bounds__(256)
void k_gemm_sk(const u16* __restrict__ A, const u16* __restrict__ BT,
               u16* __restrict__ P0, u16* __restrict__ P1, int M, int N, int K) {
    __shared__ __align__(128) char lds[2][32768];
    const int t = threadIdx.x;
    const int w = t >> 6, l = t & 63;
    const int lg = l >> 4, lr = l & 15;
    const int GX = gridDim.x, GY = gridDim.y;
    const int T = GX * GY * gridDim.z;
    const int H = blockIdx.x + blockIdx.y * GX + blockIdx.z * GX * GY;
    const int L = (H & 7) * (T >> 3) + (H >> 3);
    const int n0 = (L % GX) * 128;
    const int m0 = ((L / GX) % GY) * 128;
    const int zz = L / (GX * GY);
    const int wr = w >> 1, wc = w & 1;

    const int kh = K >> 1;
    const int kbeg = zz * kh;
    const int kend = kbeg + kh;

    const int csw = ((l & 7) ^ (l >> 3)) << 3;
    const int chunk0 = w * 4;
    const int srow = (l >> 3);

    f32x4 acc[4][4];
    #pragma unroll
    for (int i = 0; i < 4; i++)
        #pragma unroll
        for (int j = 0; j < 4; j++)
            acc[i][j] = (f32x4){0.f, 0.f, 0.f, 0.f};

    #pragma unroll
    for (int i = 0; i < 4; i++) {
        const int chunk = chunk0 + i;
        const int r = chunk * 8 + srow;
        __builtin_amdgcn_global_load_lds(GLD_AS1(A  + (size_t)(m0 + r) * K + kbeg + csw),
                                         GLD_AS3(lds[0] + chunk * 1024), 16, 0, 0);
        __builtin_amdgcn_global_load_lds(GLD_AS1(BT + (size_t)(n0 + r) * K + kbeg + csw),
                                         GLD_AS3(lds[0] + 16384 + chunk * 1024), 16, 0, 0);
    }

    int buf = 0;
    for (int kt = kbeg; kt < kend; kt += 64) {
        if (kt + 64 < kend) {
            #pragma unroll
            for (int i = 0; i < 4; i++) {
                const int chunk = chunk0 + i;
                const int r = chunk * 8 + srow;
                __builtin_amdgcn_global_load_lds(GLD_AS1(A  + (size_t)(m0 + r) * K + kt + 64 + csw),
                                                 GLD_AS3(lds[buf ^ 1] + chunk * 1024), 16, 0, 0);
                __builtin_amdgcn_global_load_lds(GLD_AS1(BT + (size_t)(n0 + r) * K + kt + 64 + csw),
                                                 GLD_AS3(lds[buf ^ 1] + 16384 + chunk * 1024), 16, 0, 0);
            }
            WAIT_BAR(8);
        } else {
            WAIT_BAR(0);
        }
        const char* Al = lds[buf];
        const char* Bl = lds[buf] + 16384;
        #pragma unroll
        for (int s = 0; s < 2; s++) {
            const int swz = (s * 64 + lg * 16) ^ ((lr & 7) << 4);
            bf16x8 af[4], bfr[4];
            #pragma unroll
            for (int mi = 0; mi < 4; mi++)
                af[mi] = *reinterpret_cast<const bf16x8*>(Al + (wr * 64 + mi * 16 + lr) * 128 + swz);
            #pragma unroll
            for (int ni = 0; ni < 4; ni++)
                bfr[ni] = *reinterpret_cast<const bf16x8*>(Bl + (wc * 64 + ni * 16 + lr) * 128 + swz);
            #pragma unroll
            for (int mi = 0; mi < 4; mi++)
                #pragma unroll
                for (int ni = 0; ni < 4; ni++)
                    acc[mi][ni] = MFMA(af[mi], bfr[ni], acc[mi][ni]);
        }
        BAR();
        buf ^= 1;
    }

    u16* dst = zz ? P1 : P0;
    #pragma unroll
    for (int mi = 0; mi < 4; mi++) {
        #pragma unroll
        for (int ni = 0; ni < 4; ni++) {
            int nn = n0 + wc * 64 + ni * 16 + lr;
            #pragma unroll
            for (int r = 0; r < 4; r++) {
                int mm = m0 + wr * 64 + mi * 16 + lg * 4 + r;
                dst[(size_t)mm * N + nn] = f2bf(acc[mi][ni][r]);
            }
        }
    }
}

// ------------- final split-K reduce: OUT = RES + P0 + P1 + bias ---------------
__global__ __launch_bounds__(256)
void k_ffreduce(const float* __restrict__ RES, const u16* __restrict__ P0,
                const u16* __restrict__ P1, const float* __restrict__ bias,
                float* __restrict__ OUT) {
    int i = blockIdx.x * 256 + threadIdx.x;      // float4 index
    float4 xv = reinterpret_cast<const float4*>(RES)[i];
    u16x4 a = reinterpret_cast<const u16x4*>(P0)[i];
    u16x4 b = reinterpret_cast<const u16x4*>(P1)[i];
    float4 bv = reinterpret_cast<const float4*>(bias)[i & (DD / 4 - 1)];
    float4 o;
    o.x = xv.x + bdec(a.x) + bdec(b.x) + bv.x;
    o.y = xv.y + bdec(a.y) + bdec(b.y) + bv.y;
    o.z = xv.z + bdec(a.z) + bdec(b.z) + bv.z;
    o.w = xv.w + bdec(a.w) + bdec(b.w) + bv.w;
    reinterpret_cast<float4*>(OUT)[i] = o;
}

// ------- flash attention, swapped-QK 32x32, KVBLK=64, cross-iter pipeline ------
// P-fragment exchange: verified shfl_xor + select build (round 12 version).
__global__ __launch_bounds__(256)
void k_attn(const u16* __restrict__ qkv, const u16* __restrict__ vT,
            u16* __restrict__ out) {
    const int w = threadIdx.x >> 6, l = threadIdx.x & 63;
    const int q = l & 31, hi = l >> 5;
    const int task = (blockIdx.x & 7) * 64 + (blockIdx.x >> 3);  // 512-block bijection
    const int bh = task >> 4;                // 0..31 (4 heads per XCD)
    const int qg = task & 15;
    const int b = bh >> 4, h = bh & 15;
    const size_t rowbase = (size_t)b * SS;
    const int q0 = (qg * 4 + w) * 32;

    __shared__ __align__(128) u16 Kl[3][64 * 64];   // triple buffer (stage depth 2)
    __shared__ __align__(128) u16 Vl[2][64 * 64];   // double buffer

    const u16* kbase = qkv + rowbase * NQKV + 1024 + h * DH;
    const u16* vbase = vT + (size_t)bh * DH * SS;

    const int srow8 = l >> 3;
    const int sslot = (l & 7) ^ srow8;
    const int kr0 = w * 8 + srow8;
    const u16* kg0 = kbase + (size_t)kr0 * NQKV + sslot * 8;
    const u16* kg1 = kbase + (size_t)(kr0 + 32) * NQKV + sslot * 8;
    const u16* vg0 = vbase + (size_t)kr0 * SS + sslot * 8;
    const u16* vg1 = vbase + (size_t)(kr0 + 32) * SS + sslot * 8;
    const int chA = (w * 8) * 64, chB = (w * 8 + 32) * 64;

    const u16* qrow = qkv + (rowbase + q0 + q) * NQKV + h * DH + hi * 8;
    bf16x8 qf[4];
    #pragma unroll
    for (int ks = 0; ks < 4; ks++)
        qf[ks] = *reinterpret_cast<const bf16x8*>(qrow + ks * 16);
    asm volatile("s_waitcnt vmcnt(0)" ::: "memory");

    bf16x8 onesf;
    #pragma unroll
    for (int i = 0; i < 8; i++) onesf[i] = (__bf16)1.0f;

    f32x16 o0 = zero16(), o1 = zero16();
    f32x16 lacc = zero16();
    const int qsw = (q & 7) << 3;

    __builtin_amdgcn_global_load_lds(GLD_AS1(kg0), GLD_AS3((u16*)Kl[0] + chA), 16, 0, 0);
    __builtin_amdgcn_global_load_lds(GLD_AS1(kg1), GLD_AS3((u16*)Kl[0] + chB), 16, 0, 0);
    __builtin_amdgcn_global_load_lds(GLD_AS1(kg0 + (size_t)64 * NQKV), GLD_AS3((u16*)Kl[1] + chA), 16, 0, 0);
    __builtin_amdgcn_global_load_lds(GLD_AS1(kg1 + (size_t)64 * NQKV), GLD_AS3((u16*)Kl[1] + chB), 16, 0, 0);
    __builtin_amdgcn_global_load_lds(GLD_AS1(vg0), GLD_AS3((u16*)Vl[0] + chA), 16, 0, 0);
    __builtin_amdgcn_global_load_lds(GLD_AS1(vg1), GLD_AS3((u16*)Vl[0] + chB), 16, 0, 0);
    WAIT_BAR(4);

    f32x16 scA0 = zero16(), scA1 = zero16();
    {
        const u16* Kb = Kl[0];
        #pragma unroll
        for (int ks = 0; ks < 4; ks++) {
            const int off = (ks * 16 + hi * 8) ^ qsw;
            bf16x8 kf0 = *reinterpret_cast<const bf16x8*>(Kb + q * 64 + off);
            bf16x8 kf1 = *reinterpret_cast<const bf16x8*>(Kb + (q + 32) * 64 + off);
            scA0 = MFMA32(kf0, qf[ks], scA0);
            scA1 = MFMA32(kf1, qf[ks], scA1);
        }
    }

    int kRead = 1, vRead = 0;
    for (int i = 0; i < 32; ++i) {
        const int kStage = (kRead == 2) ? 0 : kRead + 1;
        if (i + 2 < 32) {
            const size_t koff = (size_t)(i + 2) * 64 * NQKV;
            __builtin_amdgcn_global_load_lds(GLD_AS1(kg0 + koff), GLD_AS3((u16*)Kl[kStage] + chA), 16, 0, 0);
            __builtin_amdgcn_global_load_lds(GLD_AS1(kg1 + koff), GLD_AS3((u16*)Kl[kStage] + chB), 16, 0, 0);
            WAIT_BAR(2);
        } else {
            WAIT_BAR(0);
        }
        if (i + 1 < 32) {
            const int voff = (i + 1) * 64;
            __builtin_amdgcn_global_load_lds(GLD_AS1(vg0 + voff), GLD_AS3((u16*)Vl[vRead ^ 1] + chA), 16, 0, 0);
            __builtin_amdgcn_global_load_lds(GLD_AS1(vg1 + voff), GLD_AS3((u16*)Vl[vRead ^ 1] + chB), 16, 0, 0);
        }

        f32x16 p0, p1;
        #pragma unroll
        for (int j = 0; j < 16; j++) p0[j] = exp2f(scA0[j]);
        #pragma unroll
        for (int j = 0; j < 16; j++) p1[j] = exp2f(scA1[j]);

        f32x16 stB0 = zero16(), stB1 = zero16();
        if (i + 1 < 32) {
            const u16* Kb = Kl[kRead];
            #pragma unroll
            for (int ks = 0; ks < 4; ks++) {
                const int off = (ks * 16 + hi * 8) ^ qsw;
                bf16x8 kf0 = *reinterpret_cast<const bf16x8*>(Kb + q * 64 + off);
                bf16x8 kf1 = *reinterpret_cast<const bf16x8*>(Kb + (q + 32) * 64 + off);
                stB0 = MFMA32(kf0, qf[ks], stB0);
                stB1 = MFMA32(kf1, qf[ks], stB1);
            }
        }

        // pack P to bf16 words: pw[0..7] from p0 (kv 0-31), pw[8..15] from p1
        union W { unsigned int u; __bf16 h[2]; };
        W pw[16];
        #pragma unroll
        for (int m = 0; m < 8; m++) {
            pw[m].h[0] = (__bf16)p0[2 * m];
            pw[m].h[1] = (__bf16)p0[2 * m + 1];
            pw[8 + m].h[0] = (__bf16)p1[2 * m];
            pw[8 + m].h[1] = (__bf16)p1[2 * m + 1];
        }

        // build P B-fragments B[k=kv][n=q] for kk=0..3 (kv slices of 16)
        bf16x8 pf[4];
        #pragma unroll
        for (int kk = 0; kk < 4; kk++) {
            const int base = (kk >> 1) * 8 + (kk & 1) * 4;
            unsigned int a0 = pw[base + 0].u, a1 = pw[base + 1].u;
            unsigned int b0 = pw[base + 2].u, b1 = pw[base + 3].u;
            unsigned int own0 = hi ? b0 : a0, own1 = hi ? b1 : a1;
            unsigned int snd0 = hi ? a0 : b0, snd1 = hi ? a1 : b1;
            unsigned int r0 = __shfl_xor(snd0, 32), r1 = __shfl_xor(snd1, 32);
            union F { unsigned int u[4]; bf16x8 v; } f;
            f.u[0] = hi ? r0 : own0;
            f.u[1] = hi ? r1 : own1;
            f.u[2] = hi ? own0 : r0;
            f.u[3] = hi ? own1 : r1;
            pf[kk] = f.v;
        }

        const u16* Vb = Vl[vRead];
        #pragma unroll
        for (int kk = 0; kk < 4; kk++) {
            const int off = (kk * 16 + hi * 8) ^ qsw;
            bf16x8 v0 = *reinterpret_cast<const bf16x8*>(Vb + q * 64 + off);
            bf16x8 v1 = *reinterpret_cast<const bf16x8*>(Vb + (q + 32) * 64 + off);
            lacc = MFMA32(onesf, pf[kk], lacc);
            o0 = MFMA32(v0, pf[kk], o0);
            o1 = MFMA32(v1, pf[kk], o1);
        }

        scA0 = stB0;
        scA1 = stB1;
        kRead = kStage;
        vRead ^= 1;
    }

    float invl = 1.0f / lacc[0];
    u16* orow = out + (rowbase + q0 + q) * DD + h * DH + hi * 4;
    #pragma unroll
    for (int a = 0; a < 4; a++) {
        u16x4 s0v, s1v;
        #pragma unroll
        for (int i = 0; i < 4; i++) {
            s0v[i] = f2bf(o0[4 * a + i] * invl);
            s1v[i] = f2bf(o1[4 * a + i] * invl);
        }
        *reinterpret_cast<u16x4*>(orow + 8 * a)      = s0v;
        *reinterpret_cast<u16x4*>(orow + 32 + 8 * a) = s1v;
    }
}

extern "C" void kernel_launch(void* const* d_in, const int* in_sizes, int n_in,
                              void* d_out, int out_size, void* d_ws, size_t ws_size,
                              hipStream_t stream) {
    (void)in_sizes; (void)n_in; (void)out_size; (void)ws_size;
    const float* x     = (const float*)d_in[0];
    const float* w_qkv = (const float*)d_in[1];
    const float* w_out = (const float*)d_in[2];
    const float* b_out = (const float*)d_in[3];
    const float* g1    = (const float*)d_in[4];
    const float* be1   = (const float*)d_in[5];
    const float* g2    = (const float*)d_in[6];
    const float* be2   = (const float*)d_in[7];
    const float* w_ff1 = (const float*)d_in[8];
    const float* b_ff1 = (const float*)d_in[9];
    const float* w_ff2 = (const float*)d_in[10];
    const float* b_ff2 = (const float*)d_in[11];

    char* ws = (char*)d_ws;
    u16*   W  = (u16*)(ws);                  //  8.39 MB  (weight^T scratch, reused)
    u16*   Hb = (u16*)(ws + 8388608);        //  8.39 MB  (LN1 out; later partials)
    u16*   QF = (u16*)(ws + 16777216);       // 33.55 MB  (qkv, later ffn act)
    u16*   VT = (u16*)(ws + 50331648);       //  8.39 MB  (v^T; later partials)
    u16*   AO = (u16*)(ws + 58720256);       //  8.39 MB  (attn out; later LN2 out)
    float* X1 = (float*)(ws + 67108864);     // 16.78 MB  (post-attn residual fp32)
    float* OUT = (float*)d_out;

    // LN1: x -> Hb
    k_layernorm<<<NTOK, 256, 0, stream>>>(x, g1, be1, Hb);
    // w_qkv^T
    k_transpose<<<dim3(3072 / 32, 1024 / 32), dim3(32, 8), 0, stream>>>(w_qkv, W, 1024, 3072);
    // qkv = Hb @ w_qkv  (128^2 2-phase, XCD-swizzled; q cols pre-scaled)
    k_gemm_qkv<<<dim3(3072 / 128, 4096 / 128), 256, 0, stream>>>(
        Hb, W, QF, NTOK, NQKV, 1024);
    // V transpose (coalesced both sides)
    k_transpose_v<<<4096, 256, 0, stream>>>(QF, VT);
    // attention (512 blocks, XCD-swizzled, KVBLK=64, cross-iter pipelined)
    k_attn<<<512, 256, 0, stream>>>(QF, VT, AO);
    // w_out^T
    k_transpose<<<dim3(1024 / 32, 1024 / 32), dim3(32, 8), 0, stream>>>(w_out, W, 1024, 1024);
    // attn-out split-K x2: partials P0 -> Hb, P1 -> VT
    k_gemm_sk<<<dim3(1024 / 128, 4096 / 128, 2), 256, 0, stream>>>(
        AO, W, Hb, VT, NTOK, 1024, 1024);
    // fused: X1 = x + P0 + P1 + b_out ; AO = LN2(X1)
    k_redln<<<NTOK, 256, 0, stream>>>(x, Hb, VT, b_out, g2, be2, X1, AO);
    // w_ff1^T
    k_transpose<<<dim3(4096 / 32, 1024 / 32), dim3(32, 8), 0, stream>>>(w_ff1, W, 1024, 4096);
    // FFA = gelu(AO @ w_ff1 + b_ff1) -> QF   (256^2 fine-grained, XCD-swizzled)
    k_gemm_ff1<<<dim3(4096 / 256, 4096 / 256), 512, 0, stream>>>(
        AO, W, QF, b_ff1, NTOK, 4096, 1024);
    // w_ff2^T
    k_transpose<<<dim3(1024 / 32, 4096 / 32), dim3(32, 8), 0, stream>>>(w_ff2, W, 4096, 1024);
    // ff2 split-K x2: partials P0 -> VT, P1 -> Hb
    k_gemm_sk<<<dim3(1024 / 128, 4096 / 128, 2), 256, 0, stream>>>(
        QF, W, VT, Hb, NTOK, 1024, 4096);
    // OUT = X1 + P0 + P1 + b_ff2
    k_ffreduce<<<NTOK * DD / 4 / 256, 256, 0, stream>>>(X1, VT, Hb, b_ff2, OUT);
}